// Round 1
// baseline (1026.184 us; speedup 1.0000x reference)
//
#include <hip/hip_runtime.h>

typedef __bf16 bf16;
typedef __bf16 bf16x8 __attribute__((ext_vector_type(8)));
typedef float floatx4 __attribute__((ext_vector_type(4)));

typedef __attribute__((address_space(1))) const void gvoid_t;
typedef __attribute__((address_space(3))) void lvoid_t;

#define B_DIM 8
#define S_DIM 4096
#define M_DIM 32768
#define CHUNK 128
#define NCHUNK 32

__device__ __forceinline__ void gload_lds16(const bf16* g, bf16* l) {
    __builtin_amdgcn_global_load_lds((gvoid_t*)g, (lvoid_t*)l, 16, 0, 0);
}

__device__ __forceinline__ float gelu_tanh(float x) {
    float x3 = x * x * x;
    return 0.5f * x * (1.0f + tanhf(0.7978845608028654f * (x + 0.044715f * x3)));
}

__device__ __forceinline__ float sigmoidf(float z) {
    return 1.0f / (1.0f + expf(-z));
}

// ---------------- weight transpose (f32 -> bf16, W^T), LDS-tiled ----------------
__global__ void prep_weights(const float* __restrict__ W0, const float* __restrict__ W1,
                             const float* __restrict__ W2, const float* __restrict__ W3,
                             const float* __restrict__ W4, const float* __restrict__ W5,
                             bf16* __restrict__ T0, bf16* __restrict__ T1,
                             bf16* __restrict__ T2, bf16* __restrict__ T3,
                             bf16* __restrict__ T4, bf16* __restrict__ T5) {
    __shared__ float tile[32][33];
    int mz = blockIdx.z;
    const float* W = mz == 0 ? W0 : mz == 1 ? W1 : mz == 2 ? W2 : mz == 3 ? W3 : mz == 4 ? W4 : W5;
    bf16* T = mz == 0 ? T0 : mz == 1 ? T1 : mz == 2 ? T2 : mz == 3 ? T3 : mz == 4 ? T4 : T5;
    int tn = blockIdx.x * 32;
    int tk = blockIdx.y * 32;
    int tx = threadIdx.x & 31, ty = threadIdx.x >> 5;   // ty 0..7
#pragma unroll
    for (int i = 0; i < 4; ++i)
        tile[ty + i * 8][tx] = W[(size_t)(tk + ty + i * 8) * 1024 + tn + tx];
    __syncthreads();
#pragma unroll
    for (int i = 0; i < 4; ++i)
        T[(size_t)(tn + ty + i * 8) * 1024 + tk + tx] = (bf16)tile[tx][ty + i * 8];
}

__global__ void sp_kernel(const float* __restrict__ a_param, float* __restrict__ spbuf) {
    int d = blockIdx.x * 256 + threadIdx.x;
    spbuf[d] = log1pf(expf(a_param[d]));
}

// ---------------- gelu: x (f32) -> xg (bf16) ----------------
__global__ void gelu_kernel(const float* __restrict__ x, bf16* __restrict__ xg) {
    size_t i = (size_t)blockIdx.x * 256 + threadIdx.x;   // over n/4 elements
    float4 v = ((const float4*)x)[i];
    bf16 o0 = (bf16)gelu_tanh(v.x), o1 = (bf16)gelu_tanh(v.y);
    bf16 o2 = (bf16)gelu_tanh(v.z), o3 = (bf16)gelu_tanh(v.w);
    typedef __bf16 bf16x4 __attribute__((ext_vector_type(4)));
    bf16x4 o = {o0, o1, o2, o3};
    ((bf16x4*)xg)[i] = o;
}

// ---------------- GEMM: C[32768 x 1024] = A[32768 x 1024] * Bt[1024 x 1024]^T ----------------
// 256x256 tile, BK=64, 8 waves (2M x 4N), 128 KiB LDS double-buffer.
// 4-phase/K-tile schedule, counted vmcnt (never 0 in main loop), raw barriers,
// setprio around MFMA clusters. XOR swizzle k8 ^= (row&7) on both stage-source
// and ds_read (same involution; global_load_lds dest stays linear).
// MODE 0: outf = acc + bias              (u, f32)
// MODE 1: outh = bf16(acc + bias)        (v)
// MODE 2: outh = bf16(-8*sigmoid(acc+bias)*sp[gn])          (log_a)
// MODE 3: outh = bf16(sqrt(-expm1(2*la))*sigmoid(acc+bias)*v)  (scaled_in)
// MODE 4: outf = acc + bias + bias2 + auxf[o]               (final, +x residual)
// MODE 5: outf[o] += acc                                    (final accumulate)
template <int MODE>
__launch_bounds__(512, 2)
__global__ void gemm256(const bf16* __restrict__ A, const bf16* __restrict__ Bt,
                        float* __restrict__ outf, bf16* __restrict__ outh,
                        const float* __restrict__ bias,
                        const float* __restrict__ auxf,
                        const bf16* __restrict__ labuf,
                        const bf16* __restrict__ vbuf,
                        const float* __restrict__ bias2) {
    __shared__ __align__(16) bf16 lsA[2][2][8192];   // [buf][half(128 rows)][128*64]
    __shared__ __align__(16) bf16 lsB[2][2][8192];
    const int tid = threadIdx.x;
    const int wave = tid >> 6, lane = tid & 63;
    const int lane15 = lane & 15, quad = lane >> 4;
    const int wm = wave >> 2;            // 0..1 : A half / 128-row block
    const int wn = wave & 3;             // 0..3 : 64-col block
    const int bh = wn >> 1;              // B half this wave reads
    const int nrb = (wn & 1) * 4;        // 16-row group offset within B half

    // bijective XCD swizzle: 512 wg = 8 xcd x 64; j>>2 = m-tile, j&3 = n-tile
    const int blk = blockIdx.x;
    const int j = (blk & 7) * 64 + (blk >> 3);
    const long m0 = (long)(j >> 2) * 256;
    const long n0 = (long)(j & 3) * 256;

    // staging addressing: thread t covers LDS byte t*16 (per 64-row sub-block),
    // i.e. row = i*64 + t>>3, physical chunk = t&7 holding logical k8 = (t&7)^(row&7)
    const int sr = tid >> 3;                       // 0..63
    const int sk8 = (tid & 7) ^ (sr & 7);
    const bf16* gA = A + (size_t)(m0 + sr) * 1024 + sk8 * 8;
    const bf16* gB = Bt + (size_t)(n0 + sr) * 1024 + sk8 * 8;

    floatx4 acc[8][4] = {};
    bf16x8 af[4][2], b0[2][2], b1[2][2];

    auto SA = [&](int buf, int half, int i, int kt) {
        gload_lds16(gA + ((size_t)(half * 128 + i * 64)) * 1024 + kt * 64,
                    &lsA[buf][half][i * 4096 + wave * 512]);
    };
    auto SB = [&](int buf, int half, int i, int kt) {
        gload_lds16(gB + ((size_t)(half * 128 + i * 64)) * 1024 + kt * 64,
                    &lsB[buf][half][i * 4096 + wave * 512]);
    };
    const int c0 = quad ^ (lane15 & 7);            // swizzled chunk, kk=0; kk=1 is c0^4
    auto LDA = [&](const bf16* h, int mi, int kk) -> bf16x8 {
        return *(const bf16x8*)&h[(mi * 16 + lane15) * 64 + ((kk ? (c0 ^ 4) : c0)) * 8];
    };
    auto LDB = [&](const bf16* h, int ni, int kk) -> bf16x8 {
        return *(const bf16x8*)&h[((nrb + ni) * 16 + lane15) * 64 + ((kk ? (c0 ^ 4) : c0)) * 8];
    };

    // ---- prologue: stage K-tiles 0 and 1 (8 vmem instr each per wave) ----
    SA(0, 0, 0, 0); SA(0, 0, 1, 0); SA(0, 1, 0, 0); SA(0, 1, 1, 0);
    SB(0, 0, 0, 0); SB(0, 0, 1, 0); SB(0, 1, 0, 0); SB(0, 1, 1, 0);
    SA(1, 0, 0, 1); SA(1, 0, 1, 1); SA(1, 1, 0, 1); SA(1, 1, 1, 1);
    SB(1, 0, 0, 1); SB(1, 0, 1, 1); SB(1, 1, 0, 1); SB(1, 1, 1, 1);
    asm volatile("s_waitcnt vmcnt(8)" ::: "memory");   // tile 0 landed, tile 1 in flight
    __builtin_amdgcn_s_barrier();

    for (int kt = 0; kt < 16; ++kt) {
        const int b = kt & 1;
        const bf16* hA = &lsA[b][wm][0];
        const bf16* hB = &lsB[b][bh][0];
        const bool pf = (kt + 2 < 16);

        // ---- phase 1 : ds A(rows 0-63) + B(cols 0-31) ; MFMA Q0 ----
#pragma unroll
        for (int mi = 0; mi < 4; ++mi) { af[mi][0] = LDA(hA, mi, 0); af[mi][1] = LDA(hA, mi, 1); }
#pragma unroll
        for (int ni = 0; ni < 2; ++ni) { b0[ni][0] = LDB(hB, ni, 0); b0[ni][1] = LDB(hB, ni, 1); }
        asm volatile("s_waitcnt lgkmcnt(8)" ::: "memory");
        __builtin_amdgcn_s_barrier();
        asm volatile("s_waitcnt lgkmcnt(0)" ::: "memory");
        __builtin_amdgcn_sched_barrier(0);
        __builtin_amdgcn_s_setprio(1);
#pragma unroll
        for (int mi = 0; mi < 4; ++mi)
#pragma unroll
            for (int ni = 0; ni < 2; ++ni) {
                acc[mi][ni] = __builtin_amdgcn_mfma_f32_16x16x32_bf16(af[mi][0], b0[ni][0], acc[mi][ni], 0, 0, 0);
                acc[mi][ni] = __builtin_amdgcn_mfma_f32_16x16x32_bf16(af[mi][1], b0[ni][1], acc[mi][ni], 0, 0, 0);
            }
        __builtin_amdgcn_s_setprio(0);
        __builtin_amdgcn_s_barrier();

        // ---- phase 2 : ds B(cols 32-63) ; stage A-low(kt+2) (A rows 0-63 dead) ; MFMA Q1 ----
#pragma unroll
        for (int ni = 0; ni < 2; ++ni) { b1[ni][0] = LDB(hB, 2 + ni, 0); b1[ni][1] = LDB(hB, 2 + ni, 1); }
        if (pf) { SA(b, 0, 0, kt + 2); SA(b, 1, 0, kt + 2); }
        __builtin_amdgcn_s_barrier();
        asm volatile("s_waitcnt lgkmcnt(0)" ::: "memory");
        __builtin_amdgcn_sched_barrier(0);
        __builtin_amdgcn_s_setprio(1);
#pragma unroll
        for (int mi = 0; mi < 4; ++mi)
#pragma unroll
            for (int ni = 0; ni < 2; ++ni) {
                acc[mi][2 + ni] = __builtin_amdgcn_mfma_f32_16x16x32_bf16(af[mi][0], b1[ni][0], acc[mi][2 + ni], 0, 0, 0);
                acc[mi][2 + ni] = __builtin_amdgcn_mfma_f32_16x16x32_bf16(af[mi][1], b1[ni][1], acc[mi][2 + ni], 0, 0, 0);
            }
        __builtin_amdgcn_s_setprio(0);
        __builtin_amdgcn_s_barrier();

        // ---- phase 3 : ds A(rows 64-127) ; stage B(kt+2) (all B dead) ; MFMA Q2 ----
#pragma unroll
        for (int mi = 0; mi < 4; ++mi) { af[mi][0] = LDA(hA, 4 + mi, 0); af[mi][1] = LDA(hA, 4 + mi, 1); }
        if (pf) { SB(b, 0, 0, kt + 2); SB(b, 0, 1, kt + 2); SB(b, 1, 0, kt + 2); SB(b, 1, 1, kt + 2); }
        __builtin_amdgcn_s_barrier();
        asm volatile("s_waitcnt lgkmcnt(0)" ::: "memory");
        __builtin_amdgcn_sched_barrier(0);
        __builtin_amdgcn_s_setprio(1);
#pragma unroll
        for (int mi = 0; mi < 4; ++mi)
#pragma unroll
            for (int ni = 0; ni < 2; ++ni) {
                acc[4 + mi][2 + ni] = __builtin_amdgcn_mfma_f32_16x16x32_bf16(af[mi][0], b1[ni][0], acc[4 + mi][2 + ni], 0, 0, 0);
                acc[4 + mi][2 + ni] = __builtin_amdgcn_mfma_f32_16x16x32_bf16(af[mi][1], b1[ni][1], acc[4 + mi][2 + ni], 0, 0, 0);
            }
        __builtin_amdgcn_s_setprio(0);
        __builtin_amdgcn_s_barrier();

        // ---- phase 4 : stage A-high(kt+2) (A rows 64-127 dead) ; MFMA Q3 (reg-resident) ;
        //               counted vmcnt boundary (8 = the stages just issued this tile) ----
        if (pf) { SA(b, 0, 1, kt + 2); SA(b, 1, 1, kt + 2); }
        __builtin_amdgcn_s_barrier();
        __builtin_amdgcn_s_setprio(1);
#pragma unroll
        for (int mi = 0; mi < 4; ++mi)
#pragma unroll
            for (int ni = 0; ni < 2; ++ni) {
                acc[4 + mi][ni] = __builtin_amdgcn_mfma_f32_16x16x32_bf16(af[mi][0], b0[ni][0], acc[4 + mi][ni], 0, 0, 0);
                acc[4 + mi][ni] = __builtin_amdgcn_mfma_f32_16x16x32_bf16(af[mi][1], b0[ni][1], acc[4 + mi][ni], 0, 0, 0);
            }
        __builtin_amdgcn_s_setprio(0);
        if (pf) { asm volatile("s_waitcnt vmcnt(8)" ::: "memory"); }
        else    { asm volatile("s_waitcnt vmcnt(0)" ::: "memory"); }
        __builtin_amdgcn_s_barrier();
    }

    // ---- epilogue ----
#pragma unroll
    for (int mi = 0; mi < 8; ++mi) {
#pragma unroll
        for (int ni = 0; ni < 4; ++ni) {
            floatx4 v = acc[mi][ni];
            long gn = n0 + wn * 64 + ni * 16 + lane15;
#pragma unroll
            for (int r = 0; r < 4; ++r) {
                long gm = m0 + wm * 128 + mi * 16 + quad * 4 + r;
                size_t o = (size_t)gm * 1024 + gn;
                if (MODE == 0) {
                    outf[o] = v[r] + bias[gn];
                } else if (MODE == 1) {
                    outh[o] = (bf16)(v[r] + bias[gn]);
                } else if (MODE == 2) {
                    float z = v[r] + bias[gn];
                    outh[o] = (bf16)(-8.0f * sigmoidf(z) * auxf[gn]);
                } else if (MODE == 3) {
                    float z = v[r] + bias[gn];
                    float laf = (float)labuf[o];
                    float scv = sqrtf(-expm1f(2.0f * laf)) * sigmoidf(z) * (float)vbuf[o];
                    outh[o] = (bf16)scv;
                } else if (MODE == 4) {
                    outf[o] = v[r] + bias[gn] + bias2[gn] + auxf[o];
                } else {
                    outf[o] += v[r];
                }
            }
        }
    }
}

// ---------------- forward scan (3-pass chunked): h = a*h + u ----------------
__global__ void fscan1(const float* __restrict__ u, const float* __restrict__ a_fwd,
                       float* __restrict__ carry) {
    int d = (blockIdx.x & 3) * 256 + threadIdx.x;
    int c = (blockIdx.x >> 2) & 31;
    int b = blockIdx.x >> 7;
    float a = a_fwd[d];
    const float* up = u + ((size_t)(b * S_DIM + c * CHUNK)) * 1024 + d;
    float h = 0.0f;
#pragma unroll 8
    for (int t = 0; t < CHUNK; ++t) h = fmaf(a, h, up[(size_t)t * 1024]);
    carry[((size_t)c * 8 + b) * 1024 + d] = h;
}
__global__ void fscan2(const float* __restrict__ carry, const float* __restrict__ a_fwd,
                       float* __restrict__ H) {
    int idx = blockIdx.x * 256 + threadIdx.x;   // 8192 chains
    int d = idx & 1023, b = idx >> 10;
    float a = a_fwd[d];
    float aL = a;
#pragma unroll
    for (int i = 0; i < 7; ++i) aL *= aL;       // a^128
    float h = 0.0f;
    for (int c = 0; c < NCHUNK; ++c) {
        size_t o = ((size_t)c * 8 + b) * 1024 + d;
        H[o] = h;
        h = fmaf(aL, h, carry[o]);
    }
}
__global__ void fscan3(const float* __restrict__ u, const float* __restrict__ a_fwd,
                       const float* __restrict__ H, bf16* __restrict__ hf) {
    int d = (blockIdx.x & 3) * 256 + threadIdx.x;
    int c = (blockIdx.x >> 2) & 31;
    int b = blockIdx.x >> 7;
    float a = a_fwd[d];
    const float* up = u + ((size_t)(b * S_DIM + c * CHUNK)) * 1024 + d;
    bf16* op = hf + ((size_t)(b * S_DIM + c * CHUNK)) * 1024 + d;
    float h = H[((size_t)c * 8 + b) * 1024 + d];
#pragma unroll 4
    for (int t = 0; t < CHUNK; ++t) {
        h = fmaf(a, h, up[(size_t)t * 1024]);
        op[(size_t)t * 1024] = (bf16)h;
    }
}

// ---------------- reverse RG-LRU scan (3-pass chunked) ----------------
__global__ void bscan1(const bf16* __restrict__ la, const bf16* __restrict__ sc,
                       float* __restrict__ BL, float* __restrict__ BP) {
    int d = (blockIdx.x & 3) * 256 + threadIdx.x;
    int c = (blockIdx.x >> 2) & 31;
    int b = blockIdx.x >> 7;
    const bf16* lap = la + ((size_t)(b * S_DIM + c * CHUNK)) * 1024 + d;
    const bf16* gp = sc + ((size_t)(b * S_DIM + c * CHUNK)) * 1024 + d;
    float h = 0.0f, slog = 0.0f;
#pragma unroll 4
    for (int t = CHUNK - 1; t >= 0; --t) {
        float laf = (float)lap[(size_t)t * 1024];
        h = fmaf(expf(laf), h, (float)gp[(size_t)t * 1024]);
        slog += laf;
    }
    size_t o = ((size_t)c * 8 + b) * 1024 + d;
    BL[o] = h;
    BP[o] = expf(slog);
}
__global__ void bscan2(const float* __restrict__ BL, const float* __restrict__ BP,
                       float* __restrict__ R) {
    int idx = blockIdx.x * 256 + threadIdx.x;   // 8192 chains
    int d = idx & 1023, b = idx >> 10;
    float r = 0.0f;
    for (int c = NCHUNK - 1; c >= 0; --c) {
        size_t o = ((size_t)c * 8 + b) * 1024 + d;
        R[o] = r;                                // state entering chunk c from the right
        r = fmaf(BP[o], r, BL[o]);
    }
}
__global__ void bscan3(const bf16* __restrict__ la, const bf16* __restrict__ sc,
                       const float* __restrict__ R, bf16* __restrict__ hb) {
    int d = (blockIdx.x & 3) * 256 + threadIdx.x;
    int c = (blockIdx.x >> 2) & 31;
    int b = blockIdx.x >> 7;
    const bf16* lap = la + ((size_t)(b * S_DIM + c * CHUNK)) * 1024 + d;
    const bf16* gp = sc + ((size_t)(b * S_DIM + c * CHUNK)) * 1024 + d;
    bf16* op = hb + ((size_t)(b * S_DIM + c * CHUNK)) * 1024 + d;
    float h = R[((size_t)c * 8 + b) * 1024 + d];
#pragma unroll 4
    for (int t = CHUNK - 1; t >= 0; --t) {
        h = fmaf(expf((float)lap[(size_t)t * 1024]), h, (float)gp[(size_t)t * 1024]);
        op[(size_t)t * 1024] = (bf16)h;
    }
}

extern "C" void kernel_launch(void* const* d_in, const int* in_sizes, int n_in,
                              void* d_out, int out_size, void* d_ws, size_t ws_size,
                              hipStream_t stream) {
    const float* x       = (const float*)d_in[0];
    const float* a_fwd   = (const float*)d_in[1];
    const float* Wf1     = (const float*)d_in[2];
    const float* bf1     = (const float*)d_in[3];
    const float* Wf2     = (const float*)d_in[4];
    const float* bf2     = (const float*)d_in[5];
    const float* Wbx     = (const float*)d_in[6];
    const float* bbx     = (const float*)d_in[7];
    const float* Wgx     = (const float*)d_in[8];
    const float* bgx     = (const float*)d_in[9];
    const float* Wga     = (const float*)d_in[10];
    const float* bga     = (const float*)d_in[11];
    const float* a_param = (const float*)d_in[12];
    const float* Wb2     = (const float*)d_in[13];
    const float* bb2     = (const float*)d_in[14];
    float* out = (float*)d_out;
    (void)in_sizes; (void)n_in; (void)out_size; (void)ws_size;

    // ---- workspace layout (~209 MB total) ----
    char* ws = (char*)d_ws;
    size_t off = 0;
    const size_t WSZ = (size_t)1024 * 1024 * 2;          // 2 MB per transposed weight
    bf16* Wf1t = (bf16*)(ws + off); off += WSZ;
    bf16* Wbxt = (bf16*)(ws + off); off += WSZ;
    bf16* Wgxt = (bf16*)(ws + off); off += WSZ;
    bf16* Wgat = (bf16*)(ws + off); off += WSZ;
    bf16* Wf2t = (bf16*)(ws + off); off += WSZ;
    bf16* Wb2t = (bf16*)(ws + off); off += WSZ;
    float* spbuf = (float*)(ws + off); off += 4096;
    const size_t BSZ = (size_t)M_DIM * 1024 * 2;         // 64 MB bf16 [M][1024]
    bf16* buf0 = (bf16*)(ws + off); off += BSZ;          // xg -> hf
    bf16* buf1 = (bf16*)(ws + off); off += BSZ;          // v  -> hb
    bf16* buf2 = (bf16*)(ws + off); off += BSZ;          // la
    float* Fc = (float*)(ws + off); off += (size_t)NCHUNK * 8 * 1024 * 4;
    float* FH = (float*)(ws + off); off += (size_t)NCHUNK * 8 * 1024 * 4;
    float* BL = (float*)(ws + off); off += (size_t)NCHUNK * 8 * 1024 * 4;
    float* BP = (float*)(ws + off); off += (size_t)NCHUNK * 8 * 1024 * 4;
    float* BR = (float*)(ws + off); off += (size_t)NCHUNK * 8 * 1024 * 4;

    bf16* xg = buf0;
    bf16* hf = buf0;            // xg dead before hf written
    bf16* vb = buf1;
    bf16* hb = buf1;            // v dead before hb written
    bf16* la = buf2;
    float* u = (float*)d_out;   // d_out as f32 scratch (dead before final GEMMs)
    bf16* sc = (bf16*)d_out;    // then as bf16 scratch (dead before final GEMMs)

    // 1. prep: transposed bf16 weights + softplus(a_param)
    prep_weights<<<dim3(32, 32, 6), 256, 0, stream>>>(Wf1, Wbx, Wgx, Wga, Wf2, Wb2,
                                                      Wf1t, Wbxt, Wgxt, Wgat, Wf2t, Wb2t);
    sp_kernel<<<4, 256, 0, stream>>>(a_param, spbuf);
    // 2. gelu
    gelu_kernel<<<32768, 256, 0, stream>>>(x, xg);
    // 3. forward-branch input: u = xg@Wf1 + bf1  (f32, into d_out)
    gemm256<0><<<512, 512, 0, stream>>>(xg, Wf1t, u, nullptr, bf1, nullptr, nullptr, nullptr, nullptr);
    // 4. backward-branch input: v = xg@Wbx + bbx (bf16)
    gemm256<1><<<512, 512, 0, stream>>>(xg, Wbxt, nullptr, vb, bbx, nullptr, nullptr, nullptr, nullptr);
    // 5. forward scan -> hf (bf16, overwrites xg)
    fscan1<<<1024, 256, 0, stream>>>(u, a_fwd, Fc);
    fscan2<<<32, 256, 0, stream>>>(Fc, a_fwd, FH);
    fscan3<<<1024, 256, 0, stream>>>(u, a_fwd, FH, hf);
    // 6. gate a: la = -8*sigmoid(v@Wga+bga)*softplus(a_param)   (bf16)
    gemm256<2><<<512, 512, 0, stream>>>(vb, Wgat, nullptr, la, bga, spbuf, nullptr, nullptr, nullptr);
    // 7. gate x + scaled input: sc = sqrt(-expm1(2la))*sigmoid(v@Wgx+bgx)*v  (bf16, into d_out)
    gemm256<3><<<512, 512, 0, stream>>>(vb, Wgxt, nullptr, sc, bgx, nullptr, la, vb, nullptr);
    // 8. reverse scan -> hb (bf16, overwrites v)
    bscan1<<<1024, 256, 0, stream>>>(la, sc, BL, BP);
    bscan2<<<32, 256, 0, stream>>>(BL, BP, BR);
    bscan3<<<1024, 256, 0, stream>>>(la, sc, BR, hb);
    // 9. out = hf@Wf2 + bf2 + bb2 + x   (f32, overwrites sc in d_out)
    gemm256<4><<<512, 512, 0, stream>>>(hf, Wf2t, out, nullptr, bf2, x, nullptr, nullptr, bb2);
    // 10. out += hb@Wb2
    gemm256<5><<<512, 512, 0, stream>>>(hb, Wb2t, out, nullptr, nullptr, nullptr, nullptr, nullptr, nullptr);
}

// Round 2
// 973.903 us; speedup vs baseline: 1.0537x; 1.0537x over previous
//
#include <hip/hip_runtime.h>

typedef __bf16 bf16;
typedef __bf16 bf16x8 __attribute__((ext_vector_type(8)));
typedef float floatx4 __attribute__((ext_vector_type(4)));

typedef __attribute__((address_space(1))) const void gvoid_t;
typedef __attribute__((address_space(3))) void lvoid_t;

#define B_DIM 8
#define S_DIM 4096
#define M_DIM 32768
#define CHUNK 128
#define NCHUNK 32

__device__ __forceinline__ void gload_lds16(const bf16* g, bf16* l) {
    __builtin_amdgcn_global_load_lds((gvoid_t*)g, (lvoid_t*)l, 16, 0, 0);
}

__device__ __forceinline__ float gelu_tanh(float x) {
    float x3 = x * x * x;
    return 0.5f * x * (1.0f + tanhf(0.7978845608028654f * (x + 0.044715f * x3)));
}

__device__ __forceinline__ float sigmoidf(float z) {
    return 1.0f / (1.0f + expf(-z));
}

// ---------------- weight transpose (f32 -> bf16, W^T), LDS-tiled ----------------
__global__ void prep_weights(const float* __restrict__ W0, const float* __restrict__ W1,
                             const float* __restrict__ W2, const float* __restrict__ W3,
                             const float* __restrict__ W4, const float* __restrict__ W5,
                             bf16* __restrict__ T0, bf16* __restrict__ T1,
                             bf16* __restrict__ T2, bf16* __restrict__ T3,
                             bf16* __restrict__ T4, bf16* __restrict__ T5) {
    __shared__ float tile[32][33];
    int mz = blockIdx.z;
    const float* W = mz == 0 ? W0 : mz == 1 ? W1 : mz == 2 ? W2 : mz == 3 ? W3 : mz == 4 ? W4 : W5;
    bf16* T = mz == 0 ? T0 : mz == 1 ? T1 : mz == 2 ? T2 : mz == 3 ? T3 : mz == 4 ? T4 : T5;
    int tn = blockIdx.x * 32;
    int tk = blockIdx.y * 32;
    int tx = threadIdx.x & 31, ty = threadIdx.x >> 5;   // ty 0..7
#pragma unroll
    for (int i = 0; i < 4; ++i)
        tile[ty + i * 8][tx] = W[(size_t)(tk + ty + i * 8) * 1024 + tn + tx];
    __syncthreads();
#pragma unroll
    for (int i = 0; i < 4; ++i)
        T[(size_t)(tn + ty + i * 8) * 1024 + tk + tx] = (bf16)tile[tx][ty + i * 8];
}

__global__ void sp_kernel(const float* __restrict__ a_param, float* __restrict__ spbuf) {
    int d = blockIdx.x * 256 + threadIdx.x;
    spbuf[d] = log1pf(expf(a_param[d]));
}

// ---------------- gelu: x (f32) -> xg (bf16) ----------------
__global__ void gelu_kernel(const float* __restrict__ x, bf16* __restrict__ xg) {
    size_t i = (size_t)blockIdx.x * 256 + threadIdx.x;   // over n/4 elements
    float4 v = ((const float4*)x)[i];
    bf16 o0 = (bf16)gelu_tanh(v.x), o1 = (bf16)gelu_tanh(v.y);
    bf16 o2 = (bf16)gelu_tanh(v.z), o3 = (bf16)gelu_tanh(v.w);
    typedef __bf16 bf16x4 __attribute__((ext_vector_type(4)));
    bf16x4 o = {o0, o1, o2, o3};
    ((bf16x4*)xg)[i] = o;
}

// ---------------- GEMM: C[32768 x 1024] = A[32768 x 1024] * Bt[1024 x 1024]^T ----------------
// m201-template 8-phase schedule, 2 K-tiles per iteration, literal buffer indices
// (LICM of all LDS addresses), uniform 2 x global_load_lds per phase on the
// region-death rotation, counted vmcnt(6) at phases 4/8 only (0 on last iter),
// raw s_barrier, setprio around MFMA, NO sched_barrier (reads are compiler ds_reads).
// MODE 0: outf = acc + bias              (u, f32)
// MODE 1: outh = bf16(acc + bias)        (v)
// MODE 2: outh = bf16(-8*sigmoid(acc+bias)*sp[gn])          (log_a)
// MODE 3: outh = bf16(sqrt(-expm1(2*la))*sigmoid(acc+bias)*v)  (scaled_in)
// MODE 4: outf = acc + bias + bias2 + auxf[o]               (final, +x residual)
// MODE 5: outf[o] += acc                                    (final accumulate)
template <int MODE>
__launch_bounds__(512, 2)
__global__ void gemm256(const bf16* __restrict__ A, const bf16* __restrict__ Bt,
                        float* __restrict__ outf, bf16* __restrict__ outh,
                        const float* __restrict__ bias,
                        const float* __restrict__ auxf,
                        const bf16* __restrict__ labuf,
                        const bf16* __restrict__ vbuf,
                        const float* __restrict__ bias2) {
    __shared__ __align__(16) bf16 lsA[2][2][8192];   // [buf][half(128 rows)][128*64]
    __shared__ __align__(16) bf16 lsB[2][2][8192];
    const int tid = threadIdx.x;
    const int wave = tid >> 6, lane = tid & 63;
    const int lane15 = lane & 15, quad = lane >> 4;
    const int wm = wave >> 2;            // 0..1 : A half / 128-row block
    const int wn = wave & 3;             // 0..3 : 64-col block
    const int bh = wn >> 1;              // B half this wave reads
    const int nrb = (wn & 1) * 4;        // 16-row group offset within B half

    // bijective XCD swizzle: 512 wg = 8 xcd x 64; j>>2 = m-tile, j&3 = n-tile
    const int blk = blockIdx.x;
    const int j = (blk & 7) * 64 + (blk >> 3);
    const long m0 = (long)(j >> 2) * 256;
    const long n0 = (long)(j & 3) * 256;

    // staging: thread t covers LDS byte t*16 within one 64-row region.
    // row = t>>3, physical chunk = t&7 holds logical k8 = (t&7)^(row&7)
    const int sr = tid >> 3;                       // 0..63
    const int sk8 = (tid & 7) ^ (sr & 7);
    const bf16* gA = A + (size_t)(m0 + sr) * 1024 + sk8 * 8;
    const bf16* gB = Bt + (size_t)(n0 + sr) * 1024 + sk8 * 8;

    floatx4 acc[8][4] = {};
    bf16x8 af[4][2], b0[2][2], b1[2][2];

    auto SA = [&](int buf, int half, int i, int kt) {
        gload_lds16(gA + ((size_t)(half * 128 + i * 64)) * 1024 + (size_t)kt * 64,
                    &lsA[buf][half][i * 4096 + wave * 512]);
    };
    auto SB = [&](int buf, int half, int i, int kt) {
        gload_lds16(gB + ((size_t)(half * 128 + i * 64)) * 1024 + (size_t)kt * 64,
                    &lsB[buf][half][i * 4096 + wave * 512]);
    };
    const int sw0 = (quad ^ (lane15 & 7)) * 8;         // swizzled chunk byte-off, kk=0
    const int sw1 = ((4 + quad) ^ (lane15 & 7)) * 8;   // kk=1
    auto RDA = [&](int buf, int base) {
#pragma unroll
        for (int mi = 0; mi < 4; ++mi) {
            int r = ((base + mi) * 16 + lane15) * 64;
            af[mi][0] = *(const bf16x8*)&lsA[buf][wm][r + sw0];
            af[mi][1] = *(const bf16x8*)&lsA[buf][wm][r + sw1];
        }
    };
    auto RDB = [&](int buf, int base, bf16x8 (&bb)[2][2]) {
#pragma unroll
        for (int ni = 0; ni < 2; ++ni) {
            int r = ((nrb + base + ni) * 16 + lane15) * 64;
            bb[ni][0] = *(const bf16x8*)&lsB[buf][bh][r + sw0];
            bb[ni][1] = *(const bf16x8*)&lsB[buf][bh][r + sw1];
        }
    };
    auto MM = [&](int MB, int NB, bf16x8 (&bb)[2][2]) {
#pragma unroll
        for (int mi = 0; mi < 4; ++mi)
#pragma unroll
            for (int ni = 0; ni < 2; ++ni) {
                acc[MB + mi][NB + ni] = __builtin_amdgcn_mfma_f32_16x16x32_bf16(af[mi][0], bb[ni][0], acc[MB + mi][NB + ni], 0, 0, 0);
                acc[MB + mi][NB + ni] = __builtin_amdgcn_mfma_f32_16x16x32_bf16(af[mi][1], bb[ni][1], acc[MB + mi][NB + ni], 0, 0, 0);
            }
    };

    // ---- prologue: fully stage tile 0 (buf0) then tile 1 (buf1) ----
    SA(0, 0, 0, 0); SA(0, 0, 1, 0); SA(0, 1, 0, 0); SA(0, 1, 1, 0);
    SB(0, 0, 0, 0); SB(0, 0, 1, 0); SB(0, 1, 0, 0); SB(0, 1, 1, 0);
    SA(1, 0, 0, 1); SA(1, 0, 1, 1); SA(1, 1, 0, 1); SA(1, 1, 1, 1);
    SB(1, 0, 0, 1); SB(1, 0, 1, 1); SB(1, 1, 0, 1); SB(1, 1, 1, 1);
    asm volatile("s_waitcnt vmcnt(8)" ::: "memory");   // tile 0 landed, tile 1 in flight
    __builtin_amdgcn_s_barrier();

    for (int it = 0; it < 8; ++it) {
        const int t2 = 2 * it + 2;       // staged into buf0 this iteration
        const int t3 = 2 * it + 3;       // staged into buf1 (A-i1 completes next P1)
        const bool st = (it < 7);

        // ---- P1 (tile 2it, buf0): Q(A0,B0); stage odd-buf A-i1 of tile 2it+1 ----
        RDA(0, 0); RDB(0, 0, b0);
        if (it >= 1) { SA(1, 0, 1, 2 * it + 1); SA(1, 1, 1, 2 * it + 1); }
        asm volatile("s_waitcnt lgkmcnt(8)");
        __builtin_amdgcn_s_barrier();
        asm volatile("s_waitcnt lgkmcnt(0)");
        __builtin_amdgcn_s_setprio(1); MM(0, 0, b0); __builtin_amdgcn_s_setprio(0);
        __builtin_amdgcn_s_barrier();

        // ---- P2: Q(A0,B1); stage buf0 A-i0 (t2) -- A-i0 dead after P1 ----
        RDB(0, 2, b1);
        if (st) { SA(0, 0, 0, t2); SA(0, 1, 0, t2); }
        __builtin_amdgcn_s_barrier();
        asm volatile("s_waitcnt lgkmcnt(0)");
        __builtin_amdgcn_s_setprio(1); MM(0, 2, b1); __builtin_amdgcn_s_setprio(0);
        __builtin_amdgcn_s_barrier();

        // ---- P3: Q(A1,B1); stage buf0 B half0 (t2) -- B dead after P2 ----
        RDA(0, 4);
        if (st) { SB(0, 0, 0, t2); SB(0, 0, 1, t2); }
        __builtin_amdgcn_s_barrier();
        asm volatile("s_waitcnt lgkmcnt(0)");
        __builtin_amdgcn_s_setprio(1); MM(4, 2, b1); __builtin_amdgcn_s_setprio(0);
        __builtin_amdgcn_s_barrier();

        // ---- P4: Q(A1,B0); stage buf0 B half1 (t2); counted vmcnt ----
        if (st) { SB(0, 1, 0, t2); SB(0, 1, 1, t2); }
        __builtin_amdgcn_s_barrier();
        __builtin_amdgcn_s_setprio(1); MM(4, 0, b0); __builtin_amdgcn_s_setprio(0);
        if (st) { asm volatile("s_waitcnt vmcnt(6)" ::: "memory"); }
        else    { asm volatile("s_waitcnt vmcnt(0)" ::: "memory"); }
        __builtin_amdgcn_s_barrier();

        // ---- P5 (tile 2it+1, buf1): Q(A0,B0); stage buf0 A-i1 (t2) -- dead after P3 ----
        RDA(1, 0); RDB(1, 0, b0);
        if (st) { SA(0, 0, 1, t2); SA(0, 1, 1, t2); }
        asm volatile("s_waitcnt lgkmcnt(8)");
        __builtin_amdgcn_s_barrier();
        asm volatile("s_waitcnt lgkmcnt(0)");
        __builtin_amdgcn_s_setprio(1); MM(0, 0, b0); __builtin_amdgcn_s_setprio(0);
        __builtin_amdgcn_s_barrier();

        // ---- P6: Q(A0,B1); stage buf1 A-i0 (t3) -- dead after P5 ----
        RDB(1, 2, b1);
        if (st) { SA(1, 0, 0, t3); SA(1, 1, 0, t3); }
        __builtin_amdgcn_s_barrier();
        asm volatile("s_waitcnt lgkmcnt(0)");
        __builtin_amdgcn_s_setprio(1); MM(0, 2, b1); __builtin_amdgcn_s_setprio(0);
        __builtin_amdgcn_s_barrier();

        // ---- P7: Q(A1,B1); stage buf1 B half0 (t3) -- dead after P6 ----
        RDA(1, 4);
        if (st) { SB(1, 0, 0, t3); SB(1, 0, 1, t3); }
        __builtin_amdgcn_s_barrier();
        asm volatile("s_waitcnt lgkmcnt(0)");
        __builtin_amdgcn_s_setprio(1); MM(4, 2, b1); __builtin_amdgcn_s_setprio(0);
        __builtin_amdgcn_s_barrier();

        // ---- P8: Q(A1,B0); stage buf1 B half1 (t3); counted vmcnt ----
        if (st) { SB(1, 1, 0, t3); SB(1, 1, 1, t3); }
        __builtin_amdgcn_s_barrier();
        __builtin_amdgcn_s_setprio(1); MM(4, 0, b0); __builtin_amdgcn_s_setprio(0);
        if (st) { asm volatile("s_waitcnt vmcnt(6)" ::: "memory"); }
        else    { asm volatile("s_waitcnt vmcnt(0)" ::: "memory"); }
        __builtin_amdgcn_s_barrier();
    }

    // ---- epilogue ----
#pragma unroll
    for (int mi = 0; mi < 8; ++mi) {
#pragma unroll
        for (int ni = 0; ni < 4; ++ni) {
            floatx4 v = acc[mi][ni];
            long gn = n0 + wn * 64 + ni * 16 + lane15;
#pragma unroll
            for (int r = 0; r < 4; ++r) {
                long gm = m0 + wm * 128 + mi * 16 + quad * 4 + r;
                size_t o = (size_t)gm * 1024 + gn;
                if (MODE == 0) {
                    outf[o] = v[r] + bias[gn];
                } else if (MODE == 1) {
                    outh[o] = (bf16)(v[r] + bias[gn]);
                } else if (MODE == 2) {
                    float z = v[r] + bias[gn];
                    outh[o] = (bf16)(-8.0f * sigmoidf(z) * auxf[gn]);
                } else if (MODE == 3) {
                    float z = v[r] + bias[gn];
                    float laf = (float)labuf[o];
                    float scv = sqrtf(-expm1f(2.0f * laf)) * sigmoidf(z) * (float)vbuf[o];
                    outh[o] = (bf16)scv;
                } else if (MODE == 4) {
                    outf[o] = v[r] + bias[gn] + bias2[gn] + auxf[o];
                } else {
                    outf[o] += v[r];
                }
            }
        }
    }
}

// ---------------- forward scan (3-pass chunked): h = a*h + u ----------------
__global__ void fscan1(const float* __restrict__ u, const float* __restrict__ a_fwd,
                       float* __restrict__ carry) {
    int d = (blockIdx.x & 3) * 256 + threadIdx.x;
    int c = (blockIdx.x >> 2) & 31;
    int b = blockIdx.x >> 7;
    float a = a_fwd[d];
    const float* up = u + ((size_t)(b * S_DIM + c * CHUNK)) * 1024 + d;
    float h = 0.0f;
#pragma unroll 8
    for (int t = 0; t < CHUNK; ++t) h = fmaf(a, h, up[(size_t)t * 1024]);
    carry[((size_t)c * 8 + b) * 1024 + d] = h;
}
__global__ void fscan2(const float* __restrict__ carry, const float* __restrict__ a_fwd,
                       float* __restrict__ H) {
    int idx = blockIdx.x * 256 + threadIdx.x;   // 8192 chains
    int d = idx & 1023, b = idx >> 10;
    float a = a_fwd[d];
    float aL = a;
#pragma unroll
    for (int i = 0; i < 7; ++i) aL *= aL;       // a^128
    float h = 0.0f;
    for (int c = 0; c < NCHUNK; ++c) {
        size_t o = ((size_t)c * 8 + b) * 1024 + d;
        H[o] = h;
        h = fmaf(aL, h, carry[o]);
    }
}
__global__ void fscan3(const float* __restrict__ u, const float* __restrict__ a_fwd,
                       const float* __restrict__ H, bf16* __restrict__ hf) {
    int d = (blockIdx.x & 3) * 256 + threadIdx.x;
    int c = (blockIdx.x >> 2) & 31;
    int b = blockIdx.x >> 7;
    float a = a_fwd[d];
    const float* up = u + ((size_t)(b * S_DIM + c * CHUNK)) * 1024 + d;
    bf16* op = hf + ((size_t)(b * S_DIM + c * CHUNK)) * 1024 + d;
    float h = H[((size_t)c * 8 + b) * 1024 + d];
#pragma unroll 4
    for (int t = 0; t < CHUNK; ++t) {
        h = fmaf(a, h, up[(size_t)t * 1024]);
        op[(size_t)t * 1024] = (bf16)h;
    }
}

// ---------------- reverse RG-LRU scan (3-pass chunked) ----------------
__global__ void bscan1(const bf16* __restrict__ la, const bf16* __restrict__ sc,
                       float* __restrict__ BL, float* __restrict__ BP) {
    int d = (blockIdx.x & 3) * 256 + threadIdx.x;
    int c = (blockIdx.x >> 2) & 31;
    int b = blockIdx.x >> 7;
    const bf16* lap = la + ((size_t)(b * S_DIM + c * CHUNK)) * 1024 + d;
    const bf16* gp = sc + ((size_t)(b * S_DIM + c * CHUNK)) * 1024 + d;
    float h = 0.0f, slog = 0.0f;
#pragma unroll 4
    for (int t = CHUNK - 1; t >= 0; --t) {
        float laf = (float)lap[(size_t)t * 1024];
        h = fmaf(expf(laf), h, (float)gp[(size_t)t * 1024]);
        slog += laf;
    }
    size_t o = ((size_t)c * 8 + b) * 1024 + d;
    BL[o] = h;
    BP[o] = expf(slog);
}
__global__ void bscan2(const float* __restrict__ BL, const float* __restrict__ BP,
                       float* __restrict__ R) {
    int idx = blockIdx.x * 256 + threadIdx.x;   // 8192 chains
    int d = idx & 1023, b = idx >> 10;
    float r = 0.0f;
    for (int c = NCHUNK - 1; c >= 0; --c) {
        size_t o = ((size_t)c * 8 + b) * 1024 + d;
        R[o] = r;                                // state entering chunk c from the right
        r = fmaf(BP[o], r, BL[o]);
    }
}
__global__ void bscan3(const bf16* __restrict__ la, const bf16* __restrict__ sc,
                       const float* __restrict__ R, bf16* __restrict__ hb) {
    int d = (blockIdx.x & 3) * 256 + threadIdx.x;
    int c = (blockIdx.x >> 2) & 31;
    int b = blockIdx.x >> 7;
    const bf16* lap = la + ((size_t)(b * S_DIM + c * CHUNK)) * 1024 + d;
    const bf16* gp = sc + ((size_t)(b * S_DIM + c * CHUNK)) * 1024 + d;
    bf16* op = hb + ((size_t)(b * S_DIM + c * CHUNK)) * 1024 + d;
    float h = R[((size_t)c * 8 + b) * 1024 + d];
#pragma unroll 4
    for (int t = CHUNK - 1; t >= 0; --t) {
        h = fmaf(expf((float)lap[(size_t)t * 1024]), h, (float)gp[(size_t)t * 1024]);
        op[(size_t)t * 1024] = (bf16)h;
    }
}

extern "C" void kernel_launch(void* const* d_in, const int* in_sizes, int n_in,
                              void* d_out, int out_size, void* d_ws, size_t ws_size,
                              hipStream_t stream) {
    const float* x       = (const float*)d_in[0];
    const float* a_fwd   = (const float*)d_in[1];
    const float* Wf1     = (const float*)d_in[2];
    const float* bf1     = (const float*)d_in[3];
    const float* Wf2     = (const float*)d_in[4];
    const float* bf2     = (const float*)d_in[5];
    const float* Wbx     = (const float*)d_in[6];
    const float* bbx     = (const float*)d_in[7];
    const float* Wgx     = (const float*)d_in[8];
    const float* bgx     = (const float*)d_in[9];
    const float* Wga     = (const float*)d_in[10];
    const float* bga     = (const float*)d_in[11];
    const float* a_param = (const float*)d_in[12];
    const float* Wb2     = (const float*)d_in[13];
    const float* bb2     = (const float*)d_in[14];
    float* out = (float*)d_out;
    (void)in_sizes; (void)n_in; (void)out_size; (void)ws_size;

    // ---- workspace layout (~209 MB total) ----
    char* ws = (char*)d_ws;
    size_t off = 0;
    const size_t WSZ = (size_t)1024 * 1024 * 2;          // 2 MB per transposed weight
    bf16* Wf1t = (bf16*)(ws + off); off += WSZ;
    bf16* Wbxt = (bf16*)(ws + off); off += WSZ;
    bf16* Wgxt = (bf16*)(ws + off); off += WSZ;
    bf16* Wgat = (bf16*)(ws + off); off += WSZ;
    bf16* Wf2t = (bf16*)(ws + off); off += WSZ;
    bf16* Wb2t = (bf16*)(ws + off); off += WSZ;
    float* spbuf = (float*)(ws + off); off += 4096;
    const size_t BSZ = (size_t)M_DIM * 1024 * 2;         // 64 MB bf16 [M][1024]
    bf16* buf0 = (bf16*)(ws + off); off += BSZ;          // xg -> hf
    bf16* buf1 = (bf16*)(ws + off); off += BSZ;          // v  -> hb
    bf16* buf2 = (bf16*)(ws + off); off += BSZ;          // la
    float* Fc = (float*)(ws + off); off += (size_t)NCHUNK * 8 * 1024 * 4;
    float* FH = (float*)(ws + off); off += (size_t)NCHUNK * 8 * 1024 * 4;
    float* BL = (float*)(ws + off); off += (size_t)NCHUNK * 8 * 1024 * 4;
    float* BP = (float*)(ws + off); off += (size_t)NCHUNK * 8 * 1024 * 4;
    float* BR = (float*)(ws + off); off += (size_t)NCHUNK * 8 * 1024 * 4;

    bf16* xg = buf0;
    bf16* hf = buf0;            // xg dead before hf written
    bf16* vb = buf1;
    bf16* hb = buf1;            // v dead before hb written
    bf16* la = buf2;
    float* u = (float*)d_out;   // d_out as f32 scratch (dead before final GEMMs)
    bf16* sc = (bf16*)d_out;    // then as bf16 scratch (dead before final GEMMs)

    // 1. prep: transposed bf16 weights + softplus(a_param)
    prep_weights<<<dim3(32, 32, 6), 256, 0, stream>>>(Wf1, Wbx, Wgx, Wga, Wf2, Wb2,
                                                      Wf1t, Wbxt, Wgxt, Wgat, Wf2t, Wb2t);
    sp_kernel<<<4, 256, 0, stream>>>(a_param, spbuf);
    // 2. gelu
    gelu_kernel<<<32768, 256, 0, stream>>>(x, xg);
    // 3. forward-branch input: u = xg@Wf1 + bf1  (f32, into d_out)
    gemm256<0><<<512, 512, 0, stream>>>(xg, Wf1t, u, nullptr, bf1, nullptr, nullptr, nullptr, nullptr);
    // 4. backward-branch input: v = xg@Wbx + bbx (bf16)
    gemm256<1><<<512, 512, 0, stream>>>(xg, Wbxt, nullptr, vb, bbx, nullptr, nullptr, nullptr, nullptr);
    // 5. forward scan -> hf (bf16, overwrites xg)
    fscan1<<<1024, 256, 0, stream>>>(u, a_fwd, Fc);
    fscan2<<<32, 256, 0, stream>>>(Fc, a_fwd, FH);
    fscan3<<<1024, 256, 0, stream>>>(u, a_fwd, FH, hf);
    // 6. gate a: la = -8*sigmoid(v@Wga+bga)*softplus(a_param)   (bf16)
    gemm256<2><<<512, 512, 0, stream>>>(vb, Wgat, nullptr, la, bga, spbuf, nullptr, nullptr, nullptr);
    // 7. gate x + scaled input: sc = sqrt(-expm1(2la))*sigmoid(v@Wgx+bgx)*v  (bf16, into d_out)
    gemm256<3><<<512, 512, 0, stream>>>(vb, Wgxt, nullptr, sc, bgx, nullptr, la, vb, nullptr);
    // 8. reverse scan -> hb (bf16, overwrites v)
    bscan1<<<1024, 256, 0, stream>>>(la, sc, BL, BP);
    bscan2<<<32, 256, 0, stream>>>(BL, BP, BR);
    bscan3<<<1024, 256, 0, stream>>>(la, sc, BR, hb);
    // 9. out = hf@Wf2 + bf2 + bb2 + x   (f32, overwrites sc in d_out)
    gemm256<4><<<512, 512, 0, stream>>>(hf, Wf2t, out, nullptr, bf2, x, nullptr, nullptr, bb2);
    // 10. out += hb@Wb2
    gemm256<5><<<512, 512, 0, stream>>>(hb, Wb2t, out, nullptr, nullptr, nullptr, nullptr, nullptr, nullptr);
}

// Round 3
// 940.924 us; speedup vs baseline: 1.0906x; 1.0351x over previous
//
#include <hip/hip_runtime.h>

typedef __bf16 bf16;
typedef __bf16 bf16x8 __attribute__((ext_vector_type(8)));
typedef float floatx4 __attribute__((ext_vector_type(4)));

typedef __attribute__((address_space(1))) const void gvoid_t;
typedef __attribute__((address_space(3))) void lvoid_t;

#define B_DIM 8
#define S_DIM 4096
#define M_DIM 32768
#define CHUNK 128
#define NCHUNK 32

__device__ __forceinline__ void gload_lds16(const bf16* g, bf16* l) {
    __builtin_amdgcn_global_load_lds((gvoid_t*)g, (lvoid_t*)l, 16, 0, 0);
}

__device__ __forceinline__ float gelu_tanh(float x) {
    float x3 = x * x * x;
    return 0.5f * x * (1.0f + tanhf(0.7978845608028654f * (x + 0.044715f * x3)));
}

__device__ __forceinline__ float sigmoidf(float z) {
    return 1.0f / (1.0f + expf(-z));
}

// ---------------- weight transpose (f32 -> bf16, W^T), LDS-tiled ----------------
__global__ void prep_weights(const float* __restrict__ W0, const float* __restrict__ W1,
                             const float* __restrict__ W2, const float* __restrict__ W3,
                             const float* __restrict__ W4, const float* __restrict__ W5,
                             bf16* __restrict__ T0, bf16* __restrict__ T1,
                             bf16* __restrict__ T2, bf16* __restrict__ T3,
                             bf16* __restrict__ T4, bf16* __restrict__ T5) {
    __shared__ float tile[32][33];
    int mz = blockIdx.z;
    const float* W = mz == 0 ? W0 : mz == 1 ? W1 : mz == 2 ? W2 : mz == 3 ? W3 : mz == 4 ? W4 : W5;
    bf16* T = mz == 0 ? T0 : mz == 1 ? T1 : mz == 2 ? T2 : mz == 3 ? T3 : mz == 4 ? T4 : T5;
    int tn = blockIdx.x * 32;
    int tk = blockIdx.y * 32;
    int tx = threadIdx.x & 31, ty = threadIdx.x >> 5;   // ty 0..7
#pragma unroll
    for (int i = 0; i < 4; ++i)
        tile[ty + i * 8][tx] = W[(size_t)(tk + ty + i * 8) * 1024 + tn + tx];
    __syncthreads();
#pragma unroll
    for (int i = 0; i < 4; ++i)
        T[(size_t)(tn + ty + i * 8) * 1024 + tk + tx] = (bf16)tile[tx][ty + i * 8];
}

__global__ void sp_kernel(const float* __restrict__ a_param, float* __restrict__ spbuf) {
    int d = blockIdx.x * 256 + threadIdx.x;
    spbuf[d] = log1pf(expf(a_param[d]));
}

// ---------------- gelu: x (f32) -> xg (bf16) ----------------
__global__ void gelu_kernel(const float* __restrict__ x, bf16* __restrict__ xg) {
    size_t i = (size_t)blockIdx.x * 256 + threadIdx.x;   // over n/4 elements
    float4 v = ((const float4*)x)[i];
    bf16 o0 = (bf16)gelu_tanh(v.x), o1 = (bf16)gelu_tanh(v.y);
    bf16 o2 = (bf16)gelu_tanh(v.z), o3 = (bf16)gelu_tanh(v.w);
    typedef __bf16 bf16x4 __attribute__((ext_vector_type(4)));
    bf16x4 o = {o0, o1, o2, o3};
    ((bf16x4*)xg)[i] = o;
}

// ---------------- fused dual-B GEMM: acc0 = A@B0t^T, acc1 = A@B1t^T ----------------
// Round-0 verified 128x128 inner loop; A staged once per K-step, two B tiles,
// two accumulator sets (128 AGPR + ~96 VGPR, 2 waves/SIMD).
// PAIR 0: outf = acc0 + bias0 (u, f32) ; outh1 = bf16(acc1 + bias1) (v)
// PAIR 1: laf  = -8*sigmoid(acc0+bias0)*sp[gn]; outh0 = bf16(laf) (la)
//         outh1 = bf16(sqrt(-expm1(2*laf))*sigmoid(acc1+bias1)*vbuf[o]) (sc)
template <int PAIR>
__launch_bounds__(256, 2)
__global__ void gemm_dual(const bf16* __restrict__ A, const bf16* __restrict__ B0t,
                          const bf16* __restrict__ B1t,
                          float* __restrict__ outf, bf16* __restrict__ outh0,
                          bf16* __restrict__ outh1,
                          const float* __restrict__ bias0, const float* __restrict__ bias1,
                          const float* __restrict__ sp, const bf16* __restrict__ vbuf) {
    __shared__ __align__(16) bf16 lsA[128 * 64];
    __shared__ __align__(16) bf16 lsB0[128 * 64];
    __shared__ __align__(16) bf16 lsB1[128 * 64];
    const int tid = threadIdx.x;
    const int wave = tid >> 6;
    const int lane = tid & 63;
    const int lane15 = lane & 15;
    const int quad = lane >> 4;
    const int wm = wave & 1, wn = wave >> 1;
    const int blk = blockIdx.x;
    const int xcd = blk & 7;
    const int j = blk >> 3;                   // 0..255
    const long m0 = (long)(xcd * 32 + (j >> 3)) * 128;
    const long n0 = (long)(j & 7) * 128;
    const int r_in = lane >> 3;
    const int cch = lane & 7;

    floatx4 acc0[4][4] = {};
    floatx4 acc1[4][4] = {};

    for (int kt = 0; kt < 16; ++kt) {
        __syncthreads();
#pragma unroll
        for (int i = 0; i < 4; ++i) {
            int rr = (i * 4 + wave) * 8 + r_in;
            int g = cch ^ (rr & 7);
            size_t ga = (size_t)(m0 + rr) * 1024 + kt * 64 + g * 8;
            size_t gb = (size_t)(n0 + rr) * 1024 + kt * 64 + g * 8;
            gload_lds16(A + ga, &lsA[(i * 4 + wave) * 512]);
            gload_lds16(B0t + gb, &lsB0[(i * 4 + wave) * 512]);
            gload_lds16(B1t + gb, &lsB1[(i * 4 + wave) * 512]);
        }
        __syncthreads();
#pragma unroll
        for (int kk = 0; kk < 2; ++kk) {
            bf16x8 af[4], b0r[4], b1r[4];
#pragma unroll
            for (int mi = 0; mi < 4; ++mi) {
                int ml = wm * 64 + mi * 16 + lane15;
                af[mi] = *(const bf16x8*)&lsA[ml * 64 + ((kk * 4 + quad) ^ (ml & 7)) * 8];
            }
#pragma unroll
            for (int ni = 0; ni < 4; ++ni) {
                int nl = wn * 64 + ni * 16 + lane15;
                int so = nl * 64 + ((kk * 4 + quad) ^ (nl & 7)) * 8;
                b0r[ni] = *(const bf16x8*)&lsB0[so];
                b1r[ni] = *(const bf16x8*)&lsB1[so];
            }
#pragma unroll
            for (int mi = 0; mi < 4; ++mi)
#pragma unroll
                for (int ni = 0; ni < 4; ++ni) {
                    acc0[mi][ni] = __builtin_amdgcn_mfma_f32_16x16x32_bf16(af[mi], b0r[ni], acc0[mi][ni], 0, 0, 0);
                    acc1[mi][ni] = __builtin_amdgcn_mfma_f32_16x16x32_bf16(af[mi], b1r[ni], acc1[mi][ni], 0, 0, 0);
                }
        }
    }

#pragma unroll
    for (int mi = 0; mi < 4; ++mi) {
#pragma unroll
        for (int ni = 0; ni < 4; ++ni) {
            floatx4 v0 = acc0[mi][ni];
            floatx4 v1 = acc1[mi][ni];
            long gn = n0 + wn * 64 + ni * 16 + lane15;
#pragma unroll
            for (int r = 0; r < 4; ++r) {
                long gm = m0 + wm * 64 + mi * 16 + quad * 4 + r;
                size_t o = (size_t)gm * 1024 + gn;
                if (PAIR == 0) {
                    outf[o] = v0[r] + bias0[gn];
                    outh1[o] = (bf16)(v1[r] + bias1[gn]);
                } else {
                    float laf = -8.0f * sigmoidf(v0[r] + bias0[gn]) * sp[gn];
                    outh0[o] = (bf16)laf;
                    float scv = sqrtf(-expm1f(2.0f * laf)) * sigmoidf(v1[r] + bias1[gn]) * (float)vbuf[o];
                    outh1[o] = (bf16)scv;
                }
            }
        }
    }
}

// ---------------- concatenated-K GEMM: out = A0@B0t^T + A1@B1t^T + b0 + b1 + xres ----------------
// K=2048 (pointer switch at kt=16). Single write of the f32 output (no RMW).
__launch_bounds__(256, 2)
__global__ void gemm_cat(const bf16* __restrict__ A0, const bf16* __restrict__ A1,
                         const bf16* __restrict__ B0t, const bf16* __restrict__ B1t,
                         float* __restrict__ outf,
                         const float* __restrict__ bias0, const float* __restrict__ bias1,
                         const float* __restrict__ xres) {
    __shared__ __align__(16) bf16 lsA[128 * 64];
    __shared__ __align__(16) bf16 lsB[128 * 64];
    const int tid = threadIdx.x;
    const int wave = tid >> 6;
    const int lane = tid & 63;
    const int lane15 = lane & 15;
    const int quad = lane >> 4;
    const int wm = wave & 1, wn = wave >> 1;
    const int blk = blockIdx.x;
    const int xcd = blk & 7;
    const int j = blk >> 3;
    const long m0 = (long)(xcd * 32 + (j >> 3)) * 128;
    const long n0 = (long)(j & 7) * 128;
    const int r_in = lane >> 3;
    const int cch = lane & 7;

    floatx4 acc[4][4] = {};

    for (int kt = 0; kt < 32; ++kt) {
        const bf16* Ap = (kt < 16) ? A0 : A1;
        const bf16* Bp = (kt < 16) ? B0t : B1t;
        const int ko = kt & 15;
        __syncthreads();
#pragma unroll
        for (int i = 0; i < 4; ++i) {
            int rr = (i * 4 + wave) * 8 + r_in;
            int g = cch ^ (rr & 7);
            gload_lds16(Ap + (size_t)(m0 + rr) * 1024 + ko * 64 + g * 8, &lsA[(i * 4 + wave) * 512]);
            gload_lds16(Bp + (size_t)(n0 + rr) * 1024 + ko * 64 + g * 8, &lsB[(i * 4 + wave) * 512]);
        }
        __syncthreads();
#pragma unroll
        for (int kk = 0; kk < 2; ++kk) {
            bf16x8 af[4], bfr[4];
#pragma unroll
            for (int mi = 0; mi < 4; ++mi) {
                int ml = wm * 64 + mi * 16 + lane15;
                af[mi] = *(const bf16x8*)&lsA[ml * 64 + ((kk * 4 + quad) ^ (ml & 7)) * 8];
            }
#pragma unroll
            for (int ni = 0; ni < 4; ++ni) {
                int nl = wn * 64 + ni * 16 + lane15;
                bfr[ni] = *(const bf16x8*)&lsB[nl * 64 + ((kk * 4 + quad) ^ (nl & 7)) * 8];
            }
#pragma unroll
            for (int mi = 0; mi < 4; ++mi)
#pragma unroll
                for (int ni = 0; ni < 4; ++ni)
                    acc[mi][ni] = __builtin_amdgcn_mfma_f32_16x16x32_bf16(af[mi], bfr[ni], acc[mi][ni], 0, 0, 0);
        }
    }

#pragma unroll
    for (int mi = 0; mi < 4; ++mi) {
#pragma unroll
        for (int ni = 0; ni < 4; ++ni) {
            floatx4 v = acc[mi][ni];
            long gn = n0 + wn * 64 + ni * 16 + lane15;
#pragma unroll
            for (int r = 0; r < 4; ++r) {
                long gm = m0 + wm * 64 + mi * 16 + quad * 4 + r;
                size_t o = (size_t)gm * 1024 + gn;
                outf[o] = v[r] + bias0[gn] + bias1[gn] + xres[o];
            }
        }
    }
}

// ---------------- forward scan (3-pass chunked): h = a*h + u ----------------
__global__ void fscan1(const float* __restrict__ u, const float* __restrict__ a_fwd,
                       float* __restrict__ carry) {
    int d = (blockIdx.x & 3) * 256 + threadIdx.x;
    int c = (blockIdx.x >> 2) & 31;
    int b = blockIdx.x >> 7;
    float a = a_fwd[d];
    const float* up = u + ((size_t)(b * S_DIM + c * CHUNK)) * 1024 + d;
    float h = 0.0f;
#pragma unroll 8
    for (int t = 0; t < CHUNK; ++t) h = fmaf(a, h, up[(size_t)t * 1024]);
    carry[((size_t)c * 8 + b) * 1024 + d] = h;
}
__global__ void fscan2(const float* __restrict__ carry, const float* __restrict__ a_fwd,
                       float* __restrict__ H) {
    int idx = blockIdx.x * 256 + threadIdx.x;   // 8192 chains
    int d = idx & 1023, b = idx >> 10;
    float a = a_fwd[d];
    float aL = a;
#pragma unroll
    for (int i = 0; i < 7; ++i) aL *= aL;       // a^128
    float h = 0.0f;
    for (int c = 0; c < NCHUNK; ++c) {
        size_t o = ((size_t)c * 8 + b) * 1024 + d;
        H[o] = h;
        h = fmaf(aL, h, carry[o]);
    }
}
__global__ void fscan3(const float* __restrict__ u, const float* __restrict__ a_fwd,
                       const float* __restrict__ H, bf16* __restrict__ hf) {
    int d = (blockIdx.x & 3) * 256 + threadIdx.x;
    int c = (blockIdx.x >> 2) & 31;
    int b = blockIdx.x >> 7;
    float a = a_fwd[d];
    const float* up = u + ((size_t)(b * S_DIM + c * CHUNK)) * 1024 + d;
    bf16* op = hf + ((size_t)(b * S_DIM + c * CHUNK)) * 1024 + d;
    float h = H[((size_t)c * 8 + b) * 1024 + d];
#pragma unroll 4
    for (int t = 0; t < CHUNK; ++t) {
        h = fmaf(a, h, up[(size_t)t * 1024]);
        op[(size_t)t * 1024] = (bf16)h;
    }
}

// ---------------- reverse RG-LRU scan (3-pass chunked) ----------------
__global__ void bscan1(const bf16* __restrict__ la, const bf16* __restrict__ sc,
                       float* __restrict__ BL, float* __restrict__ BP) {
    int d = (blockIdx.x & 3) * 256 + threadIdx.x;
    int c = (blockIdx.x >> 2) & 31;
    int b = blockIdx.x >> 7;
    const bf16* lap = la + ((size_t)(b * S_DIM + c * CHUNK)) * 1024 + d;
    const bf16* gp = sc + ((size_t)(b * S_DIM + c * CHUNK)) * 1024 + d;
    float h = 0.0f, slog = 0.0f;
#pragma unroll 4
    for (int t = CHUNK - 1; t >= 0; --t) {
        float laf = (float)lap[(size_t)t * 1024];
        h = fmaf(expf(laf), h, (float)gp[(size_t)t * 1024]);
        slog += laf;
    }
    size_t o = ((size_t)c * 8 + b) * 1024 + d;
    BL[o] = h;
    BP[o] = expf(slog);
}
__global__ void bscan2(const float* __restrict__ BL, const float* __restrict__ BP,
                       float* __restrict__ R) {
    int idx = blockIdx.x * 256 + threadIdx.x;   // 8192 chains
    int d = idx & 1023, b = idx >> 10;
    float r = 0.0f;
    for (int c = NCHUNK - 1; c >= 0; --c) {
        size_t o = ((size_t)c * 8 + b) * 1024 + d;
        R[o] = r;                                // state entering chunk c from the right
        r = fmaf(BP[o], r, BL[o]);
    }
}
__global__ void bscan3(const bf16* __restrict__ la, const bf16* __restrict__ sc,
                       const float* __restrict__ R, bf16* __restrict__ hb) {
    int d = (blockIdx.x & 3) * 256 + threadIdx.x;
    int c = (blockIdx.x >> 2) & 31;
    int b = blockIdx.x >> 7;
    const bf16* lap = la + ((size_t)(b * S_DIM + c * CHUNK)) * 1024 + d;
    const bf16* gp = sc + ((size_t)(b * S_DIM + c * CHUNK)) * 1024 + d;
    bf16* op = hb + ((size_t)(b * S_DIM + c * CHUNK)) * 1024 + d;
    float h = R[((size_t)c * 8 + b) * 1024 + d];
#pragma unroll 4
    for (int t = CHUNK - 1; t >= 0; --t) {
        h = fmaf(expf((float)lap[(size_t)t * 1024]), h, (float)gp[(size_t)t * 1024]);
        op[(size_t)t * 1024] = (bf16)h;
    }
}

extern "C" void kernel_launch(void* const* d_in, const int* in_sizes, int n_in,
                              void* d_out, int out_size, void* d_ws, size_t ws_size,
                              hipStream_t stream) {
    const float* x       = (const float*)d_in[0];
    const float* a_fwd   = (const float*)d_in[1];
    const float* Wf1     = (const float*)d_in[2];
    const float* bf1     = (const float*)d_in[3];
    const float* Wf2     = (const float*)d_in[4];
    const float* bf2     = (const float*)d_in[5];
    const float* Wbx     = (const float*)d_in[6];
    const float* bbx     = (const float*)d_in[7];
    const float* Wgx     = (const float*)d_in[8];
    const float* bgx     = (const float*)d_in[9];
    const float* Wga     = (const float*)d_in[10];
    const float* bga     = (const float*)d_in[11];
    const float* a_param = (const float*)d_in[12];
    const float* Wb2     = (const float*)d_in[13];
    const float* bb2     = (const float*)d_in[14];
    float* out = (float*)d_out;
    (void)in_sizes; (void)n_in; (void)out_size; (void)ws_size;

    // ---- workspace layout (~209 MB total) ----
    char* ws = (char*)d_ws;
    size_t off = 0;
    const size_t WSZ = (size_t)1024 * 1024 * 2;          // 2 MB per transposed weight
    bf16* Wf1t = (bf16*)(ws + off); off += WSZ;
    bf16* Wbxt = (bf16*)(ws + off); off += WSZ;
    bf16* Wgxt = (bf16*)(ws + off); off += WSZ;
    bf16* Wgat = (bf16*)(ws + off); off += WSZ;
    bf16* Wf2t = (bf16*)(ws + off); off += WSZ;
    bf16* Wb2t = (bf16*)(ws + off); off += WSZ;
    float* spbuf = (float*)(ws + off); off += 4096;
    const size_t BSZ = (size_t)M_DIM * 1024 * 2;         // 64 MB bf16 [M][1024]
    bf16* buf0 = (bf16*)(ws + off); off += BSZ;          // xg -> hf
    bf16* buf1 = (bf16*)(ws + off); off += BSZ;          // v  -> hb
    bf16* buf2 = (bf16*)(ws + off); off += BSZ;          // la
    float* Fc = (float*)(ws + off); off += (size_t)NCHUNK * 8 * 1024 * 4;
    float* FH = (float*)(ws + off); off += (size_t)NCHUNK * 8 * 1024 * 4;
    float* BL = (float*)(ws + off); off += (size_t)NCHUNK * 8 * 1024 * 4;
    float* BP = (float*)(ws + off); off += (size_t)NCHUNK * 8 * 1024 * 4;
    float* BR = (float*)(ws + off); off += (size_t)NCHUNK * 8 * 1024 * 4;

    bf16* xg = buf0;
    bf16* hf = buf0;            // xg dead before hf written
    bf16* vb = buf1;
    bf16* hb = buf1;            // v dead before hb written
    bf16* la = buf2;
    float* u = (float*)d_out;   // d_out as f32 scratch (dead before dual<1>)
    bf16* sc = (bf16*)d_out;    // then as bf16 scratch (dead before gemm_cat)

    // 1. prep: transposed bf16 weights + softplus(a_param)
    prep_weights<<<dim3(32, 32, 6), 256, 0, stream>>>(Wf1, Wbx, Wgx, Wga, Wf2, Wb2,
                                                      Wf1t, Wbxt, Wgxt, Wgat, Wf2t, Wb2t);
    sp_kernel<<<4, 256, 0, stream>>>(a_param, spbuf);
    // 2. gelu
    gelu_kernel<<<32768, 256, 0, stream>>>(x, xg);
    // 3+4. fused: u = xg@Wf1 + bf1 (f32, into d_out) ; v = bf16(xg@Wbx + bbx)
    gemm_dual<0><<<2048, 256, 0, stream>>>(xg, Wf1t, Wbxt, u, nullptr, vb, bf1, bbx, nullptr, nullptr);
    // 5. forward scan -> hf (bf16, overwrites xg)
    fscan1<<<1024, 256, 0, stream>>>(u, a_fwd, Fc);
    fscan2<<<32, 256, 0, stream>>>(Fc, a_fwd, FH);
    fscan3<<<1024, 256, 0, stream>>>(u, a_fwd, FH, hf);
    // 6+7. fused: la = -8*sigmoid(v@Wga+bga)*sp ; sc = sqrt(-expm1(2la))*sigmoid(v@Wgx+bgx)*v
    gemm_dual<1><<<2048, 256, 0, stream>>>(vb, Wgat, Wgxt, nullptr, la, sc, bga, bgx, spbuf, vb);
    // 8. reverse scan -> hb (bf16, overwrites v)
    bscan1<<<1024, 256, 0, stream>>>(la, sc, BL, BP);
    bscan2<<<32, 256, 0, stream>>>(BL, BP, BR);
    bscan3<<<1024, 256, 0, stream>>>(la, sc, BR, hb);
    // 9+10. fused K=2048: out = hf@Wf2 + hb@Wb2 + bf2 + bb2 + x  (single f32 write)
    gemm_cat<<<2048, 256, 0, stream>>>(hf, hb, Wf2t, Wb2t, out, bf2, bb2, x);
}

// Round 4
// 916.229 us; speedup vs baseline: 1.1200x; 1.0270x over previous
//
#include <hip/hip_runtime.h>

typedef __bf16 bf16;
typedef __bf16 bf16x8 __attribute__((ext_vector_type(8)));
typedef float floatx4 __attribute__((ext_vector_type(4)));

typedef __attribute__((address_space(1))) const void gvoid_t;
typedef __attribute__((address_space(3))) void lvoid_t;

#define B_DIM 8
#define S_DIM 4096
#define M_DIM 32768
#define CHUNK 128
#define NCHUNK 32

__device__ __forceinline__ void gload_lds16(const bf16* g, bf16* l) {
    __builtin_amdgcn_global_load_lds((gvoid_t*)g, (lvoid_t*)l, 16, 0, 0);
}

__device__ __forceinline__ float gelu_tanh(float x) {
    float x3 = x * x * x;
    return 0.5f * x * (1.0f + tanhf(0.7978845608028654f * (x + 0.044715f * x3)));
}

__device__ __forceinline__ float sigmoidf(float z) {
    return 1.0f / (1.0f + expf(-z));
}

// ---------------- weight transpose (f32 -> bf16, W^T), LDS-tiled ----------------
__global__ void prep_weights(const float* __restrict__ W0, const float* __restrict__ W1,
                             const float* __restrict__ W2, const float* __restrict__ W3,
                             const float* __restrict__ W4, const float* __restrict__ W5,
                             bf16* __restrict__ T0, bf16* __restrict__ T1,
                             bf16* __restrict__ T2, bf16* __restrict__ T3,
                             bf16* __restrict__ T4, bf16* __restrict__ T5) {
    __shared__ float tile[32][33];
    int mz = blockIdx.z;
    const float* W = mz == 0 ? W0 : mz == 1 ? W1 : mz == 2 ? W2 : mz == 3 ? W3 : mz == 4 ? W4 : W5;
    bf16* T = mz == 0 ? T0 : mz == 1 ? T1 : mz == 2 ? T2 : mz == 3 ? T3 : mz == 4 ? T4 : T5;
    int tn = blockIdx.x * 32;
    int tk = blockIdx.y * 32;
    int tx = threadIdx.x & 31, ty = threadIdx.x >> 5;   // ty 0..7
#pragma unroll
    for (int i = 0; i < 4; ++i)
        tile[ty + i * 8][tx] = W[(size_t)(tk + ty + i * 8) * 1024 + tn + tx];
    __syncthreads();
#pragma unroll
    for (int i = 0; i < 4; ++i)
        T[(size_t)(tn + ty + i * 8) * 1024 + tk + tx] = (bf16)tile[tx][ty + i * 8];
}

__global__ void sp_kernel(const float* __restrict__ a_param, float* __restrict__ spbuf) {
    int d = blockIdx.x * 256 + threadIdx.x;
    spbuf[d] = log1pf(expf(a_param[d]));
}

// ---------------- gelu: x (f32) -> xg (bf16) ----------------
__global__ void gelu_kernel(const float* __restrict__ x, bf16* __restrict__ xg) {
    size_t i = (size_t)blockIdx.x * 256 + threadIdx.x;   // over n/4 elements
    float4 v = ((const float4*)x)[i];
    bf16 o0 = (bf16)gelu_tanh(v.x), o1 = (bf16)gelu_tanh(v.y);
    bf16 o2 = (bf16)gelu_tanh(v.z), o3 = (bf16)gelu_tanh(v.w);
    typedef __bf16 bf16x4 __attribute__((ext_vector_type(4)));
    bf16x4 o = {o0, o1, o2, o3};
    ((bf16x4*)xg)[i] = o;
}

// ---------------- GEMM: C[32768 x 1024] = A[32768 x 1024] * Bt[1024 x 1024]^T ----------------
// Round-0 verified 128x128 kernel (127 us/dispatch, 541 TF effective).
// MODE 0: outf = acc + bias              (u, f32)
// MODE 1: outh = bf16(acc + bias)        (v)
// MODE 2: outh = bf16(-8*sigmoid(acc+bias)*sp[gn])          (log_a)
// MODE 3: outh = bf16(sqrt(-expm1(2*la))*sigmoid(acc+bias)*v)  (scaled_in)
template <int MODE>
__launch_bounds__(256, 2)
__global__ void gemm_k1024(const bf16* __restrict__ A, const bf16* __restrict__ Bt,
                           float* __restrict__ outf, bf16* __restrict__ outh,
                           const float* __restrict__ bias,
                           const float* __restrict__ auxf,
                           const bf16* __restrict__ labuf,
                           const bf16* __restrict__ vbuf) {
    __shared__ __align__(16) bf16 lsA[128 * 64];
    __shared__ __align__(16) bf16 lsB[128 * 64];
    const int tid = threadIdx.x;
    const int wave = tid >> 6;
    const int lane = tid & 63;
    const int lane15 = lane & 15;
    const int quad = lane >> 4;
    const int wm = wave & 1, wn = wave >> 1;
    // XCD-aware swizzle: 2048 blocks = 8 XCDs x 32 m-tiles x 8 n-tiles
    const int blk = blockIdx.x;
    const int xcd = blk & 7;
    const int j = blk >> 3;                   // 0..255, dispatch order within XCD
    const long m0 = (long)(xcd * 32 + (j >> 3)) * 128;
    const long n0 = (long)(j & 7) * 128;
    const int r_in = lane >> 3;   // row within 8-row wave issue
    const int cch = lane & 7;     // 16B chunk within row

    floatx4 acc[4][4] = {};

    for (int kt = 0; kt < 16; ++kt) {
        __syncthreads();
#pragma unroll
        for (int i = 0; i < 4; ++i) {
            int rr = (i * 4 + wave) * 8 + r_in;
            int g = cch ^ (rr & 7);   // XOR-swizzled source chunk
            gload_lds16(A + (size_t)(m0 + rr) * 1024 + kt * 64 + g * 8, &lsA[(i * 4 + wave) * 512]);
            gload_lds16(Bt + (size_t)(n0 + rr) * 1024 + kt * 64 + g * 8, &lsB[(i * 4 + wave) * 512]);
        }
        __syncthreads();
#pragma unroll
        for (int kk = 0; kk < 2; ++kk) {
            bf16x8 af[4], bfr[4];
#pragma unroll
            for (int mi = 0; mi < 4; ++mi) {
                int ml = wm * 64 + mi * 16 + lane15;
                af[mi] = *(const bf16x8*)&lsA[ml * 64 + ((kk * 4 + quad) ^ (ml & 7)) * 8];
            }
#pragma unroll
            for (int ni = 0; ni < 4; ++ni) {
                int nl = wn * 64 + ni * 16 + lane15;
                bfr[ni] = *(const bf16x8*)&lsB[nl * 64 + ((kk * 4 + quad) ^ (nl & 7)) * 8];
            }
#pragma unroll
            for (int mi = 0; mi < 4; ++mi)
#pragma unroll
                for (int ni = 0; ni < 4; ++ni)
                    acc[mi][ni] = __builtin_amdgcn_mfma_f32_16x16x32_bf16(af[mi], bfr[ni], acc[mi][ni], 0, 0, 0);
        }
    }

#pragma unroll
    for (int mi = 0; mi < 4; ++mi) {
#pragma unroll
        for (int ni = 0; ni < 4; ++ni) {
            floatx4 v = acc[mi][ni];
            long gn = n0 + wn * 64 + ni * 16 + lane15;
#pragma unroll
            for (int r = 0; r < 4; ++r) {
                long gm = m0 + wm * 64 + mi * 16 + quad * 4 + r;
                size_t o = (size_t)gm * 1024 + gn;
                if (MODE == 0) {
                    outf[o] = v[r] + bias[gn];
                } else if (MODE == 1) {
                    outh[o] = (bf16)(v[r] + bias[gn]);
                } else if (MODE == 2) {
                    float z = v[r] + bias[gn];
                    outh[o] = (bf16)(-8.0f * sigmoidf(z) * auxf[gn]);
                } else {
                    float z = v[r] + bias[gn];
                    float laf = (float)labuf[o];
                    float sc = sqrtf(-expm1f(2.0f * laf)) * sigmoidf(z) * (float)vbuf[o];
                    outh[o] = (bf16)sc;
                }
            }
        }
    }
}

// ---------------- concatenated-K GEMM: out = A0@B0t^T + A1@B1t^T + b0 + b1 + xres ----------------
// K=2048 (pointer switch at kt=16). Single write of the f32 output (no RMW).
// Measured ~116 us in round 3 (vs 254 us for the two K=1024 GEMMs it replaces).
__launch_bounds__(256, 2)
__global__ void gemm_cat(const bf16* __restrict__ A0, const bf16* __restrict__ A1,
                         const bf16* __restrict__ B0t, const bf16* __restrict__ B1t,
                         float* __restrict__ outf,
                         const float* __restrict__ bias0, const float* __restrict__ bias1,
                         const float* __restrict__ xres) {
    __shared__ __align__(16) bf16 lsA[128 * 64];
    __shared__ __align__(16) bf16 lsB[128 * 64];
    const int tid = threadIdx.x;
    const int wave = tid >> 6;
    const int lane = tid & 63;
    const int lane15 = lane & 15;
    const int quad = lane >> 4;
    const int wm = wave & 1, wn = wave >> 1;
    const int blk = blockIdx.x;
    const int xcd = blk & 7;
    const int j = blk >> 3;
    const long m0 = (long)(xcd * 32 + (j >> 3)) * 128;
    const long n0 = (long)(j & 7) * 128;
    const int r_in = lane >> 3;
    const int cch = lane & 7;

    floatx4 acc[4][4] = {};

    for (int kt = 0; kt < 32; ++kt) {
        const bf16* Ap = (kt < 16) ? A0 : A1;
        const bf16* Bp = (kt < 16) ? B0t : B1t;
        const int ko = kt & 15;
        __syncthreads();
#pragma unroll
        for (int i = 0; i < 4; ++i) {
            int rr = (i * 4 + wave) * 8 + r_in;
            int g = cch ^ (rr & 7);
            gload_lds16(Ap + (size_t)(m0 + rr) * 1024 + ko * 64 + g * 8, &lsA[(i * 4 + wave) * 512]);
            gload_lds16(Bp + (size_t)(n0 + rr) * 1024 + ko * 64 + g * 8, &lsB[(i * 4 + wave) * 512]);
        }
        __syncthreads();
#pragma unroll
        for (int kk = 0; kk < 2; ++kk) {
            bf16x8 af[4], bfr[4];
#pragma unroll
            for (int mi = 0; mi < 4; ++mi) {
                int ml = wm * 64 + mi * 16 + lane15;
                af[mi] = *(const bf16x8*)&lsA[ml * 64 + ((kk * 4 + quad) ^ (ml & 7)) * 8];
            }
#pragma unroll
            for (int ni = 0; ni < 4; ++ni) {
                int nl = wn * 64 + ni * 16 + lane15;
                bfr[ni] = *(const bf16x8*)&lsB[nl * 64 + ((kk * 4 + quad) ^ (nl & 7)) * 8];
            }
#pragma unroll
            for (int mi = 0; mi < 4; ++mi)
#pragma unroll
                for (int ni = 0; ni < 4; ++ni)
                    acc[mi][ni] = __builtin_amdgcn_mfma_f32_16x16x32_bf16(af[mi], bfr[ni], acc[mi][ni], 0, 0, 0);
        }
    }

#pragma unroll
    for (int mi = 0; mi < 4; ++mi) {
#pragma unroll
        for (int ni = 0; ni < 4; ++ni) {
            floatx4 v = acc[mi][ni];
            long gn = n0 + wn * 64 + ni * 16 + lane15;
#pragma unroll
            for (int r = 0; r < 4; ++r) {
                long gm = m0 + wm * 64 + mi * 16 + quad * 4 + r;
                size_t o = (size_t)gm * 1024 + gn;
                outf[o] = v[r] + bias0[gn] + bias1[gn] + xres[o];
            }
        }
    }
}

// ---------------- forward scan (3-pass chunked): h = a*h + u ----------------
__global__ void fscan1(const float* __restrict__ u, const float* __restrict__ a_fwd,
                       float* __restrict__ carry) {
    int d = (blockIdx.x & 3) * 256 + threadIdx.x;
    int c = (blockIdx.x >> 2) & 31;
    int b = blockIdx.x >> 7;
    float a = a_fwd[d];
    const float* up = u + ((size_t)(b * S_DIM + c * CHUNK)) * 1024 + d;
    float h = 0.0f;
#pragma unroll 8
    for (int t = 0; t < CHUNK; ++t) h = fmaf(a, h, up[(size_t)t * 1024]);
    carry[((size_t)c * 8 + b) * 1024 + d] = h;
}
__global__ void fscan2(const float* __restrict__ carry, const float* __restrict__ a_fwd,
                       float* __restrict__ H) {
    int idx = blockIdx.x * 256 + threadIdx.x;   // 8192 chains
    int d = idx & 1023, b = idx >> 10;
    float a = a_fwd[d];
    float aL = a;
#pragma unroll
    for (int i = 0; i < 7; ++i) aL *= aL;       // a^128
    float h = 0.0f;
    for (int c = 0; c < NCHUNK; ++c) {
        size_t o = ((size_t)c * 8 + b) * 1024 + d;
        H[o] = h;
        h = fmaf(aL, h, carry[o]);
    }
}
__global__ void fscan3(const float* __restrict__ u, const float* __restrict__ a_fwd,
                       const float* __restrict__ H, bf16* __restrict__ hf) {
    int d = (blockIdx.x & 3) * 256 + threadIdx.x;
    int c = (blockIdx.x >> 2) & 31;
    int b = blockIdx.x >> 7;
    float a = a_fwd[d];
    const float* up = u + ((size_t)(b * S_DIM + c * CHUNK)) * 1024 + d;
    bf16* op = hf + ((size_t)(b * S_DIM + c * CHUNK)) * 1024 + d;
    float h = H[((size_t)c * 8 + b) * 1024 + d];
#pragma unroll 4
    for (int t = 0; t < CHUNK; ++t) {
        h = fmaf(a, h, up[(size_t)t * 1024]);
        op[(size_t)t * 1024] = (bf16)h;
    }
}

// ---------------- reverse RG-LRU scan (3-pass chunked) ----------------
__global__ void bscan1(const bf16* __restrict__ la, const bf16* __restrict__ sc,
                       float* __restrict__ BL, float* __restrict__ BP) {
    int d = (blockIdx.x & 3) * 256 + threadIdx.x;
    int c = (blockIdx.x >> 2) & 31;
    int b = blockIdx.x >> 7;
    const bf16* lap = la + ((size_t)(b * S_DIM + c * CHUNK)) * 1024 + d;
    const bf16* gp = sc + ((size_t)(b * S_DIM + c * CHUNK)) * 1024 + d;
    float h = 0.0f, slog = 0.0f;
#pragma unroll 4
    for (int t = CHUNK - 1; t >= 0; --t) {
        float laf = (float)lap[(size_t)t * 1024];
        h = fmaf(expf(laf), h, (float)gp[(size_t)t * 1024]);
        slog += laf;
    }
    size_t o = ((size_t)c * 8 + b) * 1024 + d;
    BL[o] = h;
    BP[o] = expf(slog);
}
__global__ void bscan2(const float* __restrict__ BL, const float* __restrict__ BP,
                       float* __restrict__ R) {
    int idx = blockIdx.x * 256 + threadIdx.x;   // 8192 chains
    int d = idx & 1023, b = idx >> 10;
    float r = 0.0f;
    for (int c = NCHUNK - 1; c >= 0; --c) {
        size_t o = ((size_t)c * 8 + b) * 1024 + d;
        R[o] = r;                                // state entering chunk c from the right
        r = fmaf(BP[o], r, BL[o]);
    }
}
__global__ void bscan3(const bf16* __restrict__ la, const bf16* __restrict__ sc,
                       const float* __restrict__ R, bf16* __restrict__ hb) {
    int d = (blockIdx.x & 3) * 256 + threadIdx.x;
    int c = (blockIdx.x >> 2) & 31;
    int b = blockIdx.x >> 7;
    const bf16* lap = la + ((size_t)(b * S_DIM + c * CHUNK)) * 1024 + d;
    const bf16* gp = sc + ((size_t)(b * S_DIM + c * CHUNK)) * 1024 + d;
    bf16* op = hb + ((size_t)(b * S_DIM + c * CHUNK)) * 1024 + d;
    float h = R[((size_t)c * 8 + b) * 1024 + d];
#pragma unroll 4
    for (int t = CHUNK - 1; t >= 0; --t) {
        h = fmaf(expf((float)lap[(size_t)t * 1024]), h, (float)gp[(size_t)t * 1024]);
        op[(size_t)t * 1024] = (bf16)h;
    }
}

extern "C" void kernel_launch(void* const* d_in, const int* in_sizes, int n_in,
                              void* d_out, int out_size, void* d_ws, size_t ws_size,
                              hipStream_t stream) {
    const float* x       = (const float*)d_in[0];
    const float* a_fwd   = (const float*)d_in[1];
    const float* Wf1     = (const float*)d_in[2];
    const float* bf1     = (const float*)d_in[3];
    const float* Wf2     = (const float*)d_in[4];
    const float* bf2     = (const float*)d_in[5];
    const float* Wbx     = (const float*)d_in[6];
    const float* bbx     = (const float*)d_in[7];
    const float* Wgx     = (const float*)d_in[8];
    const float* bgx     = (const float*)d_in[9];
    const float* Wga     = (const float*)d_in[10];
    const float* bga     = (const float*)d_in[11];
    const float* a_param = (const float*)d_in[12];
    const float* Wb2     = (const float*)d_in[13];
    const float* bb2     = (const float*)d_in[14];
    float* out = (float*)d_out;
    (void)in_sizes; (void)n_in; (void)out_size; (void)ws_size;

    // ---- workspace layout (~209 MB total) ----
    char* ws = (char*)d_ws;
    size_t off = 0;
    const size_t WSZ = (size_t)1024 * 1024 * 2;          // 2 MB per transposed weight
    bf16* Wf1t = (bf16*)(ws + off); off += WSZ;
    bf16* Wbxt = (bf16*)(ws + off); off += WSZ;
    bf16* Wgxt = (bf16*)(ws + off); off += WSZ;
    bf16* Wgat = (bf16*)(ws + off); off += WSZ;
    bf16* Wf2t = (bf16*)(ws + off); off += WSZ;
    bf16* Wb2t = (bf16*)(ws + off); off += WSZ;
    float* spbuf = (float*)(ws + off); off += 4096;
    const size_t BSZ = (size_t)M_DIM * 1024 * 2;         // 64 MB bf16 [M][1024]
    bf16* buf0 = (bf16*)(ws + off); off += BSZ;          // xg -> hf
    bf16* buf1 = (bf16*)(ws + off); off += BSZ;          // v  -> hb
    bf16* buf2 = (bf16*)(ws + off); off += BSZ;          // la
    float* Fc = (float*)(ws + off); off += (size_t)NCHUNK * 8 * 1024 * 4;
    float* FH = (float*)(ws + off); off += (size_t)NCHUNK * 8 * 1024 * 4;
    float* BL = (float*)(ws + off); off += (size_t)NCHUNK * 8 * 1024 * 4;
    float* BP = (float*)(ws + off); off += (size_t)NCHUNK * 8 * 1024 * 4;
    float* BR = (float*)(ws + off); off += (size_t)NCHUNK * 8 * 1024 * 4;

    bf16* xg = buf0;
    bf16* hf = buf0;            // xg dead before hf written
    bf16* vb = buf1;
    bf16* hb = buf1;            // v dead before hb written
    bf16* la = buf2;
    float* u = (float*)d_out;   // d_out as f32 scratch (dead before gemm_cat)
    bf16* sc = (bf16*)d_out;    // then as bf16 scratch (dead before gemm_cat)

    // 1. prep: transposed bf16 weights + softplus(a_param)
    prep_weights<<<dim3(32, 32, 6), 256, 0, stream>>>(Wf1, Wbx, Wgx, Wga, Wf2, Wb2,
                                                      Wf1t, Wbxt, Wgxt, Wgat, Wf2t, Wb2t);
    sp_kernel<<<4, 256, 0, stream>>>(a_param, spbuf);
    // 2. gelu
    gelu_kernel<<<32768, 256, 0, stream>>>(x, xg);
    // 3. forward-branch input: u = xg@Wf1 + bf1  (f32, into d_out)
    gemm_k1024<0><<<2048, 256, 0, stream>>>(xg, Wf1t, u, nullptr, bf1, nullptr, nullptr, nullptr);
    // 4. backward-branch input: v = xg@Wbx + bbx (bf16)
    gemm_k1024<1><<<2048, 256, 0, stream>>>(xg, Wbxt, nullptr, vb, bbx, nullptr, nullptr, nullptr);
    // 5. forward scan -> hf (bf16, overwrites xg)
    fscan1<<<1024, 256, 0, stream>>>(u, a_fwd, Fc);
    fscan2<<<32, 256, 0, stream>>>(Fc, a_fwd, FH);
    fscan3<<<1024, 256, 0, stream>>>(u, a_fwd, FH, hf);
    // 6. gate a: la = -8*sigmoid(v@Wga+bga)*softplus(a_param)   (bf16)
    gemm_k1024<2><<<2048, 256, 0, stream>>>(vb, Wgat, nullptr, la, bga, spbuf, nullptr, nullptr);
    // 7. gate x + scaled input: sc = sqrt(-expm1(2la))*sigmoid(v@Wgx+bgx)*v  (bf16, into d_out)
    gemm_k1024<3><<<2048, 256, 0, stream>>>(vb, Wgxt, nullptr, sc, bgx, nullptr, la, vb);
    // 8. reverse scan -> hb (bf16, overwrites v)
    bscan1<<<1024, 256, 0, stream>>>(la, sc, BL, BP);
    bscan2<<<32, 256, 0, stream>>>(BL, BP, BR);
    bscan3<<<1024, 256, 0, stream>>>(la, sc, BR, hb);
    // 9+10. fused K=2048: out = hf@Wf2 + hb@Wb2 + bf2 + bb2 + x  (single f32 write)
    gemm_cat<<<2048, 256, 0, stream>>>(hf, hb, Wf2t, Wb2t, out, bf2, bb2, x);
}

// Round 5
// 906.364 us; speedup vs baseline: 1.1322x; 1.0109x over previous
//
#include <hip/hip_runtime.h>

typedef __bf16 bf16;
typedef __bf16 bf16x8 __attribute__((ext_vector_type(8)));
typedef float floatx4 __attribute__((ext_vector_type(4)));

typedef __attribute__((address_space(1))) const void gvoid_t;
typedef __attribute__((address_space(3))) void lvoid_t;

#define B_DIM 8
#define S_DIM 4096
#define M_DIM 32768
#define CHUNK 128
#define NCHUNK 32

__device__ __forceinline__ void gload_lds16(const bf16* g, bf16* l) {
    __builtin_amdgcn_global_load_lds((gvoid_t*)g, (lvoid_t*)l, 16, 0, 0);
}

__device__ __forceinline__ float gelu_tanh(float x) {
    float x3 = x * x * x;
    return 0.5f * x * (1.0f + tanhf(0.7978845608028654f * (x + 0.044715f * x3)));
}

__device__ __forceinline__ float sigmoidf(float z) {
    return 1.0f / (1.0f + expf(-z));
}

// ---------------- weight transpose (f32 -> bf16, W^T), LDS-tiled ----------------
__global__ void prep_weights(const float* __restrict__ W0, const float* __restrict__ W1,
                             const float* __restrict__ W2, const float* __restrict__ W3,
                             const float* __restrict__ W4, const float* __restrict__ W5,
                             bf16* __restrict__ T0, bf16* __restrict__ T1,
                             bf16* __restrict__ T2, bf16* __restrict__ T3,
                             bf16* __restrict__ T4, bf16* __restrict__ T5) {
    __shared__ float tile[32][33];
    int mz = blockIdx.z;
    const float* W = mz == 0 ? W0 : mz == 1 ? W1 : mz == 2 ? W2 : mz == 3 ? W3 : mz == 4 ? W4 : W5;
    bf16* T = mz == 0 ? T0 : mz == 1 ? T1 : mz == 2 ? T2 : mz == 3 ? T3 : mz == 4 ? T4 : T5;
    int tn = blockIdx.x * 32;
    int tk = blockIdx.y * 32;
    int tx = threadIdx.x & 31, ty = threadIdx.x >> 5;   // ty 0..7
#pragma unroll
    for (int i = 0; i < 4; ++i)
        tile[ty + i * 8][tx] = W[(size_t)(tk + ty + i * 8) * 1024 + tn + tx];
    __syncthreads();
#pragma unroll
    for (int i = 0; i < 4; ++i)
        T[(size_t)(tn + ty + i * 8) * 1024 + tk + tx] = (bf16)tile[tx][ty + i * 8];
}

__global__ void sp_kernel(const float* __restrict__ a_param, float* __restrict__ spbuf) {
    int d = blockIdx.x * 256 + threadIdx.x;
    spbuf[d] = log1pf(expf(a_param[d]));
}

// ---------------- gelu: x (f32) -> xg (bf16) ----------------
__global__ void gelu_kernel(const float* __restrict__ x, bf16* __restrict__ xg) {
    size_t i = (size_t)blockIdx.x * 256 + threadIdx.x;   // over n/4 elements
    float4 v = ((const float4*)x)[i];
    bf16 o0 = (bf16)gelu_tanh(v.x), o1 = (bf16)gelu_tanh(v.y);
    bf16 o2 = (bf16)gelu_tanh(v.z), o3 = (bf16)gelu_tanh(v.w);
    typedef __bf16 bf16x4 __attribute__((ext_vector_type(4)));
    bf16x4 o = {o0, o1, o2, o3};
    ((bf16x4*)xg)[i] = o;
}

// ---------------- GEMM: C[32768 x 1024] = A[32768 x 1024] * Bt[1024 x 1024]^T ----------------
// 128x256 tile, 8 waves (512 threads), per-wave 64x64 sub-tile = round-0 verified
// inner loop (acc 4x4, XOR-swizzled staging/reads). 6 gloads/thread/K-step (was 8),
// 1024 WGs, 2 WG/CU (16 waves/CU). F-amortization: 2x work per WG per K-step.
// MODE 0: outf = acc + bias              (u, f32)
// MODE 1: outh = bf16(acc + bias)        (v)
// MODE 2: outh = bf16(-8*sigmoid(acc+bias)*sp[gn])          (log_a)
// MODE 3: outh = bf16(sqrt(-expm1(2*la))*sigmoid(acc+bias)*v)  (scaled_in)
template <int MODE>
__launch_bounds__(512, 4)
__global__ void gemm_w(const bf16* __restrict__ A, const bf16* __restrict__ Bt,
                       float* __restrict__ outf, bf16* __restrict__ outh,
                       const float* __restrict__ bias,
                       const float* __restrict__ auxf,
                       const bf16* __restrict__ labuf,
                       const bf16* __restrict__ vbuf) {
    __shared__ __align__(16) bf16 lsA[2][4096];   // 2 x [64 rows][64 k] regions
    __shared__ __align__(16) bf16 lsB[4][4096];   // 4 x [64 rows][64 k] regions
    const int tid = threadIdx.x;
    const int wave = tid >> 6;
    const int lane = tid & 63;
    const int lane15 = lane & 15;
    const int quad = lane >> 4;
    const int wm = wave >> 2;            // 0..1 : 64-row block of A
    const int wn = wave & 3;             // 0..3 : 64-col block of C (B region)
    // XCD-aware swizzle: 1024 blocks = 8 XCDs x 32 m-tiles x 4 n-tiles
    const int blk = blockIdx.x;
    const int xcd = blk & 7;
    const int j = blk >> 3;                     // 0..127
    const long m0 = (long)(xcd * 32 + (j >> 2)) * 128;
    const long n0 = (long)(j & 3) * 256;
    // staging: thread t -> row-in-region sr = t>>3, physical chunk t&7 holds
    // logical k8-chunk (t&7)^(sr&7)
    const int sr = tid >> 3;                    // 0..63
    const int sk8 = (tid & 7) ^ (sr & 7);
    const bf16* gA = A + (size_t)(m0 + sr) * 1024 + sk8 * 8;
    const bf16* gB = Bt + (size_t)(n0 + sr) * 1024 + sk8 * 8;

    floatx4 acc[4][4] = {};

    for (int kt = 0; kt < 16; ++kt) {
        __syncthreads();
        gload_lds16(gA + (size_t)kt * 64, &lsA[0][tid * 8]);
        gload_lds16(gA + (size_t)64 * 1024 + kt * 64, &lsA[1][tid * 8]);
#pragma unroll
        for (int i = 0; i < 4; ++i)
            gload_lds16(gB + (size_t)(i * 64) * 1024 + kt * 64, &lsB[i][tid * 8]);
        __syncthreads();
#pragma unroll
        for (int kk = 0; kk < 2; ++kk) {
            bf16x8 af[4], bfr[4];
#pragma unroll
            for (int mi = 0; mi < 4; ++mi) {
                int rl = mi * 16 + lane15;
                af[mi] = *(const bf16x8*)&lsA[wm][rl * 64 + ((kk * 4 + quad) ^ (rl & 7)) * 8];
            }
#pragma unroll
            for (int ni = 0; ni < 4; ++ni) {
                int rl = ni * 16 + lane15;
                bfr[ni] = *(const bf16x8*)&lsB[wn][rl * 64 + ((kk * 4 + quad) ^ (rl & 7)) * 8];
            }
#pragma unroll
            for (int mi = 0; mi < 4; ++mi)
#pragma unroll
                for (int ni = 0; ni < 4; ++ni)
                    acc[mi][ni] = __builtin_amdgcn_mfma_f32_16x16x32_bf16(af[mi], bfr[ni], acc[mi][ni], 0, 0, 0);
        }
    }

#pragma unroll
    for (int mi = 0; mi < 4; ++mi) {
#pragma unroll
        for (int ni = 0; ni < 4; ++ni) {
            floatx4 v = acc[mi][ni];
            long gn = n0 + wn * 64 + ni * 16 + lane15;
#pragma unroll
            for (int r = 0; r < 4; ++r) {
                long gm = m0 + wm * 64 + mi * 16 + quad * 4 + r;
                size_t o = (size_t)gm * 1024 + gn;
                if (MODE == 0) {
                    outf[o] = v[r] + bias[gn];
                } else if (MODE == 1) {
                    outh[o] = (bf16)(v[r] + bias[gn]);
                } else if (MODE == 2) {
                    float z = v[r] + bias[gn];
                    outh[o] = (bf16)(-8.0f * sigmoidf(z) * auxf[gn]);
                } else {
                    float z = v[r] + bias[gn];
                    float laf = (float)labuf[o];
                    float sc = sqrtf(-expm1f(2.0f * laf)) * sigmoidf(z) * (float)vbuf[o];
                    outh[o] = (bf16)sc;
                }
            }
        }
    }
}

// ---------------- concatenated-K GEMM: out = A0@B0t^T + A1@B1t^T + b0 + b1 + xres ----------------
// K=2048 (pointer switch at kt=16), same 128x256 / 8-wave shape. Single f32 write.
__launch_bounds__(512, 4)
__global__ void gemm_cat(const bf16* __restrict__ A0, const bf16* __restrict__ A1,
                         const bf16* __restrict__ B0t, const bf16* __restrict__ B1t,
                         float* __restrict__ outf,
                         const float* __restrict__ bias0, const float* __restrict__ bias1,
                         const float* __restrict__ xres) {
    __shared__ __align__(16) bf16 lsA[2][4096];
    __shared__ __align__(16) bf16 lsB[4][4096];
    const int tid = threadIdx.x;
    const int wave = tid >> 6;
    const int lane = tid & 63;
    const int lane15 = lane & 15;
    const int quad = lane >> 4;
    const int wm = wave >> 2;
    const int wn = wave & 3;
    const int blk = blockIdx.x;
    const int xcd = blk & 7;
    const int j = blk >> 3;
    const long m0 = (long)(xcd * 32 + (j >> 2)) * 128;
    const long n0 = (long)(j & 3) * 256;
    const int sr = tid >> 3;
    const int sk8 = (tid & 7) ^ (sr & 7);

    floatx4 acc[4][4] = {};

    for (int kt = 0; kt < 32; ++kt) {
        const bf16* Ap = (kt < 16) ? A0 : A1;
        const bf16* Bp = (kt < 16) ? B0t : B1t;
        const int ko = kt & 15;
        const bf16* gA = Ap + (size_t)(m0 + sr) * 1024 + sk8 * 8 + (size_t)ko * 64;
        const bf16* gB = Bp + (size_t)(n0 + sr) * 1024 + sk8 * 8 + (size_t)ko * 64;
        __syncthreads();
        gload_lds16(gA, &lsA[0][tid * 8]);
        gload_lds16(gA + (size_t)64 * 1024, &lsA[1][tid * 8]);
#pragma unroll
        for (int i = 0; i < 4; ++i)
            gload_lds16(gB + (size_t)(i * 64) * 1024, &lsB[i][tid * 8]);
        __syncthreads();
#pragma unroll
        for (int kk = 0; kk < 2; ++kk) {
            bf16x8 af[4], bfr[4];
#pragma unroll
            for (int mi = 0; mi < 4; ++mi) {
                int rl = mi * 16 + lane15;
                af[mi] = *(const bf16x8*)&lsA[wm][rl * 64 + ((kk * 4 + quad) ^ (rl & 7)) * 8];
            }
#pragma unroll
            for (int ni = 0; ni < 4; ++ni) {
                int rl = ni * 16 + lane15;
                bfr[ni] = *(const bf16x8*)&lsB[wn][rl * 64 + ((kk * 4 + quad) ^ (rl & 7)) * 8];
            }
#pragma unroll
            for (int mi = 0; mi < 4; ++mi)
#pragma unroll
                for (int ni = 0; ni < 4; ++ni)
                    acc[mi][ni] = __builtin_amdgcn_mfma_f32_16x16x32_bf16(af[mi], bfr[ni], acc[mi][ni], 0, 0, 0);
        }
    }

#pragma unroll
    for (int mi = 0; mi < 4; ++mi) {
#pragma unroll
        for (int ni = 0; ni < 4; ++ni) {
            floatx4 v = acc[mi][ni];
            long gn = n0 + wn * 64 + ni * 16 + lane15;
#pragma unroll
            for (int r = 0; r < 4; ++r) {
                long gm = m0 + wm * 64 + mi * 16 + quad * 4 + r;
                size_t o = (size_t)gm * 1024 + gn;
                outf[o] = v[r] + bias0[gn] + bias1[gn] + xres[o];
            }
        }
    }
}

// ---------------- forward scan (3-pass chunked): h = a*h + u ----------------
__global__ void fscan1(const float* __restrict__ u, const float* __restrict__ a_fwd,
                       float* __restrict__ carry) {
    int d = (blockIdx.x & 3) * 256 + threadIdx.x;
    int c = (blockIdx.x >> 2) & 31;
    int b = blockIdx.x >> 7;
    float a = a_fwd[d];
    const float* up = u + ((size_t)(b * S_DIM + c * CHUNK)) * 1024 + d;
    float h = 0.0f;
#pragma unroll 8
    for (int t = 0; t < CHUNK; ++t) h = fmaf(a, h, up[(size_t)t * 1024]);
    carry[((size_t)c * 8 + b) * 1024 + d] = h;
}
__global__ void fscan2(const float* __restrict__ carry, const float* __restrict__ a_fwd,
                       float* __restrict__ H) {
    int idx = blockIdx.x * 256 + threadIdx.x;   // 8192 chains
    int d = idx & 1023, b = idx >> 10;
    float a = a_fwd[d];
    float aL = a;
#pragma unroll
    for (int i = 0; i < 7; ++i) aL *= aL;       // a^128
    float h = 0.0f;
    for (int c = 0; c < NCHUNK; ++c) {
        size_t o = ((size_t)c * 8 + b) * 1024 + d;
        H[o] = h;
        h = fmaf(aL, h, carry[o]);
    }
}
__global__ void fscan3(const float* __restrict__ u, const float* __restrict__ a_fwd,
                       const float* __restrict__ H, bf16* __restrict__ hf) {
    int d = (blockIdx.x & 3) * 256 + threadIdx.x;
    int c = (blockIdx.x >> 2) & 31;
    int b = blockIdx.x >> 7;
    float a = a_fwd[d];
    const float* up = u + ((size_t)(b * S_DIM + c * CHUNK)) * 1024 + d;
    bf16* op = hf + ((size_t)(b * S_DIM + c * CHUNK)) * 1024 + d;
    float h = H[((size_t)c * 8 + b) * 1024 + d];
#pragma unroll 4
    for (int t = 0; t < CHUNK; ++t) {
        h = fmaf(a, h, up[(size_t)t * 1024]);
        op[(size_t)t * 1024] = (bf16)h;
    }
}

// ---------------- reverse RG-LRU scan (3-pass chunked) ----------------
__global__ void bscan1(const bf16* __restrict__ la, const bf16* __restrict__ sc,
                       float* __restrict__ BL, float* __restrict__ BP) {
    int d = (blockIdx.x & 3) * 256 + threadIdx.x;
    int c = (blockIdx.x >> 2) & 31;
    int b = blockIdx.x >> 7;
    const bf16* lap = la + ((size_t)(b * S_DIM + c * CHUNK)) * 1024 + d;
    const bf16* gp = sc + ((size_t)(b * S_DIM + c * CHUNK)) * 1024 + d;
    float h = 0.0f, slog = 0.0f;
#pragma unroll 4
    for (int t = CHUNK - 1; t >= 0; --t) {
        float laf = (float)lap[(size_t)t * 1024];
        h = fmaf(expf(laf), h, (float)gp[(size_t)t * 1024]);
        slog += laf;
    }
    size_t o = ((size_t)c * 8 + b) * 1024 + d;
    BL[o] = h;
    BP[o] = expf(slog);
}
__global__ void bscan2(const float* __restrict__ BL, const float* __restrict__ BP,
                       float* __restrict__ R) {
    int idx = blockIdx.x * 256 + threadIdx.x;   // 8192 chains
    int d = idx & 1023, b = idx >> 10;
    float r = 0.0f;
    for (int c = NCHUNK - 1; c >= 0; --c) {
        size_t o = ((size_t)c * 8 + b) * 1024 + d;
        R[o] = r;                                // state entering chunk c from the right
        r = fmaf(BP[o], r, BL[o]);
    }
}
__global__ void bscan3(const bf16* __restrict__ la, const bf16* __restrict__ sc,
                       const float* __restrict__ R, bf16* __restrict__ hb) {
    int d = (blockIdx.x & 3) * 256 + threadIdx.x;
    int c = (blockIdx.x >> 2) & 31;
    int b = blockIdx.x >> 7;
    const bf16* lap = la + ((size_t)(b * S_DIM + c * CHUNK)) * 1024 + d;
    const bf16* gp = sc + ((size_t)(b * S_DIM + c * CHUNK)) * 1024 + d;
    bf16* op = hb + ((size_t)(b * S_DIM + c * CHUNK)) * 1024 + d;
    float h = R[((size_t)c * 8 + b) * 1024 + d];
#pragma unroll 4
    for (int t = CHUNK - 1; t >= 0; --t) {
        h = fmaf(expf((float)lap[(size_t)t * 1024]), h, (float)gp[(size_t)t * 1024]);
        op[(size_t)t * 1024] = (bf16)h;
    }
}

extern "C" void kernel_launch(void* const* d_in, const int* in_sizes, int n_in,
                              void* d_out, int out_size, void* d_ws, size_t ws_size,
                              hipStream_t stream) {
    const float* x       = (const float*)d_in[0];
    const float* a_fwd   = (const float*)d_in[1];
    const float* Wf1     = (const float*)d_in[2];
    const float* bf1     = (const float*)d_in[3];
    const float* Wf2     = (const float*)d_in[4];
    const float* bf2     = (const float*)d_in[5];
    const float* Wbx     = (const float*)d_in[6];
    const float* bbx     = (const float*)d_in[7];
    const float* Wgx     = (const float*)d_in[8];
    const float* bgx     = (const float*)d_in[9];
    const float* Wga     = (const float*)d_in[10];
    const float* bga     = (const float*)d_in[11];
    const float* a_param = (const float*)d_in[12];
    const float* Wb2     = (const float*)d_in[13];
    const float* bb2     = (const float*)d_in[14];
    float* out = (float*)d_out;
    (void)in_sizes; (void)n_in; (void)out_size; (void)ws_size;

    // ---- workspace layout (~209 MB total) ----
    char* ws = (char*)d_ws;
    size_t off = 0;
    const size_t WSZ = (size_t)1024 * 1024 * 2;          // 2 MB per transposed weight
    bf16* Wf1t = (bf16*)(ws + off); off += WSZ;
    bf16* Wbxt = (bf16*)(ws + off); off += WSZ;
    bf16* Wgxt = (bf16*)(ws + off); off += WSZ;
    bf16* Wgat = (bf16*)(ws + off); off += WSZ;
    bf16* Wf2t = (bf16*)(ws + off); off += WSZ;
    bf16* Wb2t = (bf16*)(ws + off); off += WSZ;
    float* spbuf = (float*)(ws + off); off += 4096;
    const size_t BSZ = (size_t)M_DIM * 1024 * 2;         // 64 MB bf16 [M][1024]
    bf16* buf0 = (bf16*)(ws + off); off += BSZ;          // xg -> hf
    bf16* buf1 = (bf16*)(ws + off); off += BSZ;          // v  -> hb
    bf16* buf2 = (bf16*)(ws + off); off += BSZ;          // la
    float* Fc = (float*)(ws + off); off += (size_t)NCHUNK * 8 * 1024 * 4;
    float* FH = (float*)(ws + off); off += (size_t)NCHUNK * 8 * 1024 * 4;
    float* BL = (float*)(ws + off); off += (size_t)NCHUNK * 8 * 1024 * 4;
    float* BP = (float*)(ws + off); off += (size_t)NCHUNK * 8 * 1024 * 4;
    float* BR = (float*)(ws + off); off += (size_t)NCHUNK * 8 * 1024 * 4;

    bf16* xg = buf0;
    bf16* hf = buf0;            // xg dead before hf written
    bf16* vb = buf1;
    bf16* hb = buf1;            // v dead before hb written
    bf16* la = buf2;
    float* u = (float*)d_out;   // d_out as f32 scratch (dead before gemm_cat)
    bf16* sc = (bf16*)d_out;    // then as bf16 scratch (dead before gemm_cat)

    // 1. prep: transposed bf16 weights + softplus(a_param)
    prep_weights<<<dim3(32, 32, 6), 256, 0, stream>>>(Wf1, Wbx, Wgx, Wga, Wf2, Wb2,
                                                      Wf1t, Wbxt, Wgxt, Wgat, Wf2t, Wb2t);
    sp_kernel<<<4, 256, 0, stream>>>(a_param, spbuf);
    // 2. gelu
    gelu_kernel<<<32768, 256, 0, stream>>>(x, xg);
    // 3. forward-branch input: u = xg@Wf1 + bf1  (f32, into d_out)
    gemm_w<0><<<1024, 512, 0, stream>>>(xg, Wf1t, u, nullptr, bf1, nullptr, nullptr, nullptr);
    // 4. backward-branch input: v = xg@Wbx + bbx (bf16)
    gemm_w<1><<<1024, 512, 0, stream>>>(xg, Wbxt, nullptr, vb, bbx, nullptr, nullptr, nullptr);
    // 5. forward scan -> hf (bf16, overwrites xg)
    fscan1<<<1024, 256, 0, stream>>>(u, a_fwd, Fc);
    fscan2<<<32, 256, 0, stream>>>(Fc, a_fwd, FH);
    fscan3<<<1024, 256, 0, stream>>>(u, a_fwd, FH, hf);
    // 6. gate a: la = -8*sigmoid(v@Wga+bga)*softplus(a_param)   (bf16)
    gemm_w<2><<<1024, 512, 0, stream>>>(vb, Wgat, nullptr, la, bga, spbuf, nullptr, nullptr);
    // 7. gate x + scaled input: sc = sqrt(-expm1(2la))*sigmoid(v@Wgx+bgx)*v  (bf16, into d_out)
    gemm_w<3><<<1024, 512, 0, stream>>>(vb, Wgxt, nullptr, sc, bgx, nullptr, la, vb);
    // 8. reverse scan -> hb (bf16, overwrites v)
    bscan1<<<1024, 256, 0, stream>>>(la, sc, BL, BP);
    bscan2<<<32, 256, 0, stream>>>(BL, BP, BR);
    bscan3<<<1024, 256, 0, stream>>>(la, sc, BR, hb);
    // 9+10. fused K=2048: out = hf@Wf2 + hb@Wb2 + bf2 + bb2 + x  (single f32 write)
    gemm_cat<<<1024, 512, 0, stream>>>(hf, hb, Wf2t, Wb2t, out, bf2, bb2, x);
}

// Round 6
// 883.727 us; speedup vs baseline: 1.1612x; 1.0256x over previous
//
#include <hip/hip_runtime.h>

typedef __bf16 bf16;
typedef __bf16 bf16x2 __attribute__((ext_vector_type(2)));
typedef __bf16 bf16x8 __attribute__((ext_vector_type(8)));
typedef float floatx4 __attribute__((ext_vector_type(4)));

typedef __attribute__((address_space(1))) const void gvoid_t;
typedef __attribute__((address_space(3))) void lvoid_t;

#define B_DIM 8
#define S_DIM 4096
#define M_DIM 32768
#define CHUNK 128
#define NCHUNK 32

__device__ __forceinline__ void gload_lds16(const bf16* g, bf16* l) {
    __builtin_amdgcn_global_load_lds((gvoid_t*)g, (lvoid_t*)l, 16, 0, 0);
}

__device__ __forceinline__ float gelu_tanh(float x) {
    float x3 = x * x * x;
    return 0.5f * x * (1.0f + tanhf(0.7978845608028654f * (x + 0.044715f * x3)));
}

__device__ __forceinline__ float sigmoidf(float z) {
    return 1.0f / (1.0f + expf(-z));
}

// ---------------- weight transpose (f32 -> bf16, W^T), LDS-tiled ----------------
__global__ void prep_weights(const float* __restrict__ W0, const float* __restrict__ W1,
                             const float* __restrict__ W2, const float* __restrict__ W3,
                             const float* __restrict__ W4, const float* __restrict__ W5,
                             bf16* __restrict__ T0, bf16* __restrict__ T1,
                             bf16* __restrict__ T2, bf16* __restrict__ T3,
                             bf16* __restrict__ T4, bf16* __restrict__ T5) {
    __shared__ float tile[32][33];
    int mz = blockIdx.z;
    const float* W = mz == 0 ? W0 : mz == 1 ? W1 : mz == 2 ? W2 : mz == 3 ? W3 : mz == 4 ? W4 : W5;
    bf16* T = mz == 0 ? T0 : mz == 1 ? T1 : mz == 2 ? T2 : mz == 3 ? T3 : mz == 4 ? T4 : T5;
    int tn = blockIdx.x * 32;
    int tk = blockIdx.y * 32;
    int tx = threadIdx.x & 31, ty = threadIdx.x >> 5;   // ty 0..7
#pragma unroll
    for (int i = 0; i < 4; ++i)
        tile[ty + i * 8][tx] = W[(size_t)(tk + ty + i * 8) * 1024 + tn + tx];
    __syncthreads();
#pragma unroll
    for (int i = 0; i < 4; ++i)
        T[(size_t)(tn + ty + i * 8) * 1024 + tk + tx] = (bf16)tile[tx][ty + i * 8];
}

__global__ void sp_kernel(const float* __restrict__ a_param, float* __restrict__ spbuf) {
    int d = blockIdx.x * 256 + threadIdx.x;
    spbuf[d] = log1pf(expf(a_param[d]));
}

// ---------------- gelu: x (f32) -> xg (bf16) ----------------
__global__ void gelu_kernel(const float* __restrict__ x, bf16* __restrict__ xg) {
    size_t i = (size_t)blockIdx.x * 256 + threadIdx.x;   // over n/4 elements
    float4 v = ((const float4*)x)[i];
    bf16 o0 = (bf16)gelu_tanh(v.x), o1 = (bf16)gelu_tanh(v.y);
    bf16 o2 = (bf16)gelu_tanh(v.z), o3 = (bf16)gelu_tanh(v.w);
    typedef __bf16 bf16x4 __attribute__((ext_vector_type(4)));
    bf16x4 o = {o0, o1, o2, o3};
    ((bf16x4*)xg)[i] = o;
}

// ---------------- merged GEMM 3+4: C[32768 x 2048] = xg @ [Wf1 | Wbx] ----------------
// 128x256 tile, 8 waves; N=2048 via weight concatenation (Wf1t, Wbxt adjacent in ws).
// n<1024 -> u (bf16), else -> v (bf16). One A fetch serves both weight matrices.
__launch_bounds__(512, 4)
__global__ void gemm_f01(const bf16* __restrict__ A, const bf16* __restrict__ Bt,
                         bf16* __restrict__ ubuf, bf16* __restrict__ vbuf,
                         const float* __restrict__ bias0, const float* __restrict__ bias1) {
    __shared__ __align__(16) bf16 lsA[2][4096];
    __shared__ __align__(16) bf16 lsB[4][4096];
    const int tid = threadIdx.x;
    const int wave = tid >> 6;
    const int lane = tid & 63;
    const int lane15 = lane & 15;
    const int quad = lane >> 4;
    const int wm = wave >> 2;
    const int wn = wave & 3;
    // 2048 WGs = 8 XCDs x (32 m-tiles x 8 n-tiles)
    const int blk = blockIdx.x;
    const int xcd = blk & 7;
    const int j = blk >> 3;                     // 0..255
    const long m0 = (long)(xcd * 32 + (j >> 3)) * 128;
    const long n0 = (long)(j & 7) * 256;        // 0..1792
    const int sr = tid >> 3;
    const int sk8 = (tid & 7) ^ (sr & 7);
    const bf16* gA = A + (size_t)(m0 + sr) * 1024 + sk8 * 8;
    const bf16* gB = Bt + (size_t)(n0 + sr) * 1024 + sk8 * 8;

    floatx4 acc[4][4] = {};

    for (int kt = 0; kt < 16; ++kt) {
        __syncthreads();
        gload_lds16(gA + (size_t)kt * 64, &lsA[0][tid * 8]);
        gload_lds16(gA + (size_t)64 * 1024 + kt * 64, &lsA[1][tid * 8]);
#pragma unroll
        for (int i = 0; i < 4; ++i)
            gload_lds16(gB + (size_t)(i * 64) * 1024 + kt * 64, &lsB[i][tid * 8]);
        __syncthreads();
#pragma unroll
        for (int kk = 0; kk < 2; ++kk) {
            bf16x8 af[4], bfr[4];
#pragma unroll
            for (int mi = 0; mi < 4; ++mi) {
                int rl = mi * 16 + lane15;
                af[mi] = *(const bf16x8*)&lsA[wm][rl * 64 + ((kk * 4 + quad) ^ (rl & 7)) * 8];
            }
#pragma unroll
            for (int ni = 0; ni < 4; ++ni) {
                int rl = ni * 16 + lane15;
                bfr[ni] = *(const bf16x8*)&lsB[wn][rl * 64 + ((kk * 4 + quad) ^ (rl & 7)) * 8];
            }
#pragma unroll
            for (int mi = 0; mi < 4; ++mi)
#pragma unroll
                for (int ni = 0; ni < 4; ++ni)
                    acc[mi][ni] = __builtin_amdgcn_mfma_f32_16x16x32_bf16(af[mi], bfr[ni], acc[mi][ni], 0, 0, 0);
        }
    }

    const bool isU = (n0 < 1024);               // uniform per WG (n0 multiple of 256)
    bf16* outp = isU ? ubuf : vbuf;
    const float* bp = isU ? bias0 : bias1;
    const long nb = isU ? n0 : (n0 - 1024);
#pragma unroll
    for (int mi = 0; mi < 4; ++mi) {
#pragma unroll
        for (int ni = 0; ni < 4; ++ni) {
            floatx4 v = acc[mi][ni];
            long gn = nb + wn * 64 + ni * 16 + lane15;
#pragma unroll
            for (int r = 0; r < 4; ++r) {
                long gm = m0 + wm * 64 + mi * 16 + quad * 4 + r;
                outp[(size_t)gm * 1024 + gn] = (bf16)(v[r] + bp[gn]);
            }
        }
    }
}

// ---------------- GEMM: C[32768 x 1024] = A[32768 x 1024] * Bt[1024 x 1024]^T ----------------
// 128x256 tile, 8 waves (512 threads), per-wave 64x64 sub-tile.
// MODE 2: outh = bf16(-8*sigmoid(acc+bias)*sp[gn])          (log_a)
// MODE 3: outh = bf16(sqrt(-expm1(2*la))*sigmoid(acc+bias)*v)  (scaled_in)
template <int MODE>
__launch_bounds__(512, 4)
__global__ void gemm_w(const bf16* __restrict__ A, const bf16* __restrict__ Bt,
                       bf16* __restrict__ outh,
                       const float* __restrict__ bias,
                       const float* __restrict__ auxf,
                       const bf16* __restrict__ labuf,
                       const bf16* __restrict__ vbuf) {
    __shared__ __align__(16) bf16 lsA[2][4096];   // 2 x [64 rows][64 k] regions
    __shared__ __align__(16) bf16 lsB[4][4096];   // 4 x [64 rows][64 k] regions
    const int tid = threadIdx.x;
    const int wave = tid >> 6;
    const int lane = tid & 63;
    const int lane15 = lane & 15;
    const int quad = lane >> 4;
    const int wm = wave >> 2;
    const int wn = wave & 3;
    // 1024 blocks = 8 XCDs x 32 m-tiles x 4 n-tiles
    const int blk = blockIdx.x;
    const int xcd = blk & 7;
    const int j = blk >> 3;                     // 0..127
    const long m0 = (long)(xcd * 32 + (j >> 2)) * 128;
    const long n0 = (long)(j & 3) * 256;
    const int sr = tid >> 3;
    const int sk8 = (tid & 7) ^ (sr & 7);
    const bf16* gA = A + (size_t)(m0 + sr) * 1024 + sk8 * 8;
    const bf16* gB = Bt + (size_t)(n0 + sr) * 1024 + sk8 * 8;

    floatx4 acc[4][4] = {};

    for (int kt = 0; kt < 16; ++kt) {
        __syncthreads();
        gload_lds16(gA + (size_t)kt * 64, &lsA[0][tid * 8]);
        gload_lds16(gA + (size_t)64 * 1024 + kt * 64, &lsA[1][tid * 8]);
#pragma unroll
        for (int i = 0; i < 4; ++i)
            gload_lds16(gB + (size_t)(i * 64) * 1024 + kt * 64, &lsB[i][tid * 8]);
        __syncthreads();
#pragma unroll
        for (int kk = 0; kk < 2; ++kk) {
            bf16x8 af[4], bfr[4];
#pragma unroll
            for (int mi = 0; mi < 4; ++mi) {
                int rl = mi * 16 + lane15;
                af[mi] = *(const bf16x8*)&lsA[wm][rl * 64 + ((kk * 4 + quad) ^ (rl & 7)) * 8];
            }
#pragma unroll
            for (int ni = 0; ni < 4; ++ni) {
                int rl = ni * 16 + lane15;
                bfr[ni] = *(const bf16x8*)&lsB[wn][rl * 64 + ((kk * 4 + quad) ^ (rl & 7)) * 8];
            }
#pragma unroll
            for (int mi = 0; mi < 4; ++mi)
#pragma unroll
                for (int ni = 0; ni < 4; ++ni)
                    acc[mi][ni] = __builtin_amdgcn_mfma_f32_16x16x32_bf16(af[mi], bfr[ni], acc[mi][ni], 0, 0, 0);
        }
    }

#pragma unroll
    for (int mi = 0; mi < 4; ++mi) {
#pragma unroll
        for (int ni = 0; ni < 4; ++ni) {
            floatx4 v = acc[mi][ni];
            long gn = n0 + wn * 64 + ni * 16 + lane15;
#pragma unroll
            for (int r = 0; r < 4; ++r) {
                long gm = m0 + wm * 64 + mi * 16 + quad * 4 + r;
                size_t o = (size_t)gm * 1024 + gn;
                if (MODE == 2) {
                    float z = v[r] + bias[gn];
                    outh[o] = (bf16)(-8.0f * sigmoidf(z) * auxf[gn]);
                } else {
                    float z = v[r] + bias[gn];
                    float laf = (float)labuf[o];
                    float sc = sqrtf(-expm1f(2.0f * laf)) * sigmoidf(z) * (float)vbuf[o];
                    outh[o] = (bf16)sc;
                }
            }
        }
    }
}

// ---------------- concatenated-K GEMM: out = A0@B0t^T + A1@B1t^T + b0 + b1 + xres ----------------
// K=2048 (pointer switch at kt=16), 128x256 / 8-wave. Single f32 write.
__launch_bounds__(512, 4)
__global__ void gemm_cat(const bf16* __restrict__ A0, const bf16* __restrict__ A1,
                         const bf16* __restrict__ B0t, const bf16* __restrict__ B1t,
                         float* __restrict__ outf,
                         const float* __restrict__ bias0, const float* __restrict__ bias1,
                         const float* __restrict__ xres) {
    __shared__ __align__(16) bf16 lsA[2][4096];
    __shared__ __align__(16) bf16 lsB[4][4096];
    const int tid = threadIdx.x;
    const int wave = tid >> 6;
    const int lane = tid & 63;
    const int lane15 = lane & 15;
    const int quad = lane >> 4;
    const int wm = wave >> 2;
    const int wn = wave & 3;
    const int blk = blockIdx.x;
    const int xcd = blk & 7;
    const int j = blk >> 3;
    const long m0 = (long)(xcd * 32 + (j >> 2)) * 128;
    const long n0 = (long)(j & 3) * 256;
    const int sr = tid >> 3;
    const int sk8 = (tid & 7) ^ (sr & 7);

    floatx4 acc[4][4] = {};

    for (int kt = 0; kt < 32; ++kt) {
        const bf16* Ap = (kt < 16) ? A0 : A1;
        const bf16* Bp = (kt < 16) ? B0t : B1t;
        const int ko = kt & 15;
        const bf16* gA = Ap + (size_t)(m0 + sr) * 1024 + sk8 * 8 + (size_t)ko * 64;
        const bf16* gB = Bp + (size_t)(n0 + sr) * 1024 + sk8 * 8 + (size_t)ko * 64;
        __syncthreads();
        gload_lds16(gA, &lsA[0][tid * 8]);
        gload_lds16(gA + (size_t)64 * 1024, &lsA[1][tid * 8]);
#pragma unroll
        for (int i = 0; i < 4; ++i)
            gload_lds16(gB + (size_t)(i * 64) * 1024, &lsB[i][tid * 8]);
        __syncthreads();
#pragma unroll
        for (int kk = 0; kk < 2; ++kk) {
            bf16x8 af[4], bfr[4];
#pragma unroll
            for (int mi = 0; mi < 4; ++mi) {
                int rl = mi * 16 + lane15;
                af[mi] = *(const bf16x8*)&lsA[wm][rl * 64 + ((kk * 4 + quad) ^ (rl & 7)) * 8];
            }
#pragma unroll
            for (int ni = 0; ni < 4; ++ni) {
                int rl = ni * 16 + lane15;
                bfr[ni] = *(const bf16x8*)&lsB[wn][rl * 64 + ((kk * 4 + quad) ^ (rl & 7)) * 8];
            }
#pragma unroll
            for (int mi = 0; mi < 4; ++mi)
#pragma unroll
                for (int ni = 0; ni < 4; ++ni)
                    acc[mi][ni] = __builtin_amdgcn_mfma_f32_16x16x32_bf16(af[mi], bfr[ni], acc[mi][ni], 0, 0, 0);
        }
    }

#pragma unroll
    for (int mi = 0; mi < 4; ++mi) {
#pragma unroll
        for (int ni = 0; ni < 4; ++ni) {
            floatx4 v = acc[mi][ni];
            long gn = n0 + wn * 64 + ni * 16 + lane15;
#pragma unroll
            for (int r = 0; r < 4; ++r) {
                long gm = m0 + wm * 64 + mi * 16 + quad * 4 + r;
                size_t o = (size_t)gm * 1024 + gn;
                outf[o] = v[r] + bias0[gn] + bias1[gn] + xres[o];
            }
        }
    }
}

// ---------------- forward scan (3-pass chunked): h = a*h + u ----------------
// u is bf16; each thread owns two adjacent d channels (4 B/lane loads).
__global__ void fscan1(const bf16* __restrict__ u, const float* __restrict__ a_fwd,
                       float* __restrict__ carry) {
    int dg = blockIdx.x & 1;
    int c = (blockIdx.x >> 1) & 31;
    int b = blockIdx.x >> 6;
    int d = (dg * 256 + threadIdx.x) * 2;
    float a0 = a_fwd[d], a1 = a_fwd[d + 1];
    const bf16* up = u + ((size_t)(b * S_DIM + c * CHUNK)) * 1024 + d;
    float h0 = 0.0f, h1 = 0.0f;
#pragma unroll 8
    for (int t = 0; t < CHUNK; ++t) {
        bf16x2 w = *(const bf16x2*)(up + (size_t)t * 1024);
        h0 = fmaf(a0, h0, (float)w[0]);
        h1 = fmaf(a1, h1, (float)w[1]);
    }
    size_t o = ((size_t)c * 8 + b) * 1024 + d;
    carry[o] = h0;
    carry[o + 1] = h1;
}
__global__ void fscan2(const float* __restrict__ carry, const float* __restrict__ a_fwd,
                       float* __restrict__ H) {
    int idx = blockIdx.x * 256 + threadIdx.x;   // 8192 chains
    int d = idx & 1023, b = idx >> 10;
    float a = a_fwd[d];
    float aL = a;
#pragma unroll
    for (int i = 0; i < 7; ++i) aL *= aL;       // a^128
    float h = 0.0f;
    for (int c = 0; c < NCHUNK; ++c) {
        size_t o = ((size_t)c * 8 + b) * 1024 + d;
        H[o] = h;
        h = fmaf(aL, h, carry[o]);
    }
}
__global__ void fscan3(const bf16* __restrict__ u, const float* __restrict__ a_fwd,
                       const float* __restrict__ H, bf16* __restrict__ hf) {
    int dg = blockIdx.x & 1;
    int c = (blockIdx.x >> 1) & 31;
    int b = blockIdx.x >> 6;
    int d = (dg * 256 + threadIdx.x) * 2;
    float a0 = a_fwd[d], a1 = a_fwd[d + 1];
    const bf16* up = u + ((size_t)(b * S_DIM + c * CHUNK)) * 1024 + d;
    bf16* op = hf + ((size_t)(b * S_DIM + c * CHUNK)) * 1024 + d;
    size_t ho = ((size_t)c * 8 + b) * 1024 + d;
    float h0 = H[ho], h1 = H[ho + 1];
#pragma unroll 4
    for (int t = 0; t < CHUNK; ++t) {
        bf16x2 w = *(const bf16x2*)(up + (size_t)t * 1024);
        h0 = fmaf(a0, h0, (float)w[0]);
        h1 = fmaf(a1, h1, (float)w[1]);
        bf16x2 ov; ov[0] = (bf16)h0; ov[1] = (bf16)h1;
        *(bf16x2*)(op + (size_t)t * 1024) = ov;
    }
}

// ---------------- reverse RG-LRU scan (3-pass chunked) ----------------
__global__ void bscan1(const bf16* __restrict__ la, const bf16* __restrict__ sc,
                       float* __restrict__ BL, float* __restrict__ BP) {
    int dg = blockIdx.x & 1;
    int c = (blockIdx.x >> 1) & 31;
    int b = blockIdx.x >> 6;
    int d = (dg * 256 + threadIdx.x) * 2;
    const bf16* lap = la + ((size_t)(b * S_DIM + c * CHUNK)) * 1024 + d;
    const bf16* gp = sc + ((size_t)(b * S_DIM + c * CHUNK)) * 1024 + d;
    float h0 = 0.0f, h1 = 0.0f, s0 = 0.0f, s1 = 0.0f;
#pragma unroll 4
    for (int t = CHUNK - 1; t >= 0; --t) {
        bf16x2 lw = *(const bf16x2*)(lap + (size_t)t * 1024);
        bf16x2 gw = *(const bf16x2*)(gp + (size_t)t * 1024);
        float l0 = (float)lw[0], l1 = (float)lw[1];
        h0 = fmaf(expf(l0), h0, (float)gw[0]);
        h1 = fmaf(expf(l1), h1, (float)gw[1]);
        s0 += l0;
        s1 += l1;
    }
    size_t o = ((size_t)c * 8 + b) * 1024 + d;
    BL[o] = h0; BL[o + 1] = h1;
    BP[o] = expf(s0); BP[o + 1] = expf(s1);
}
__global__ void bscan2(const float* __restrict__ BL, const float* __restrict__ BP,
                       float* __restrict__ R) {
    int idx = blockIdx.x * 256 + threadIdx.x;   // 8192 chains
    int d = idx & 1023, b = idx >> 10;
    float r = 0.0f;
    for (int c = NCHUNK - 1; c >= 0; --c) {
        size_t o = ((size_t)c * 8 + b) * 1024 + d;
        R[o] = r;                                // state entering chunk c from the right
        r = fmaf(BP[o], r, BL[o]);
    }
}
__global__ void bscan3(const bf16* __restrict__ la, const bf16* __restrict__ sc,
                       const float* __restrict__ R, bf16* __restrict__ hb) {
    int dg = blockIdx.x & 1;
    int c = (blockIdx.x >> 1) & 31;
    int b = blockIdx.x >> 6;
    int d = (dg * 256 + threadIdx.x) * 2;
    const bf16* lap = la + ((size_t)(b * S_DIM + c * CHUNK)) * 1024 + d;
    const bf16* gp = sc + ((size_t)(b * S_DIM + c * CHUNK)) * 1024 + d;
    bf16* op = hb + ((size_t)(b * S_DIM + c * CHUNK)) * 1024 + d;
    size_t ro = ((size_t)c * 8 + b) * 1024 + d;
    float h0 = R[ro], h1 = R[ro + 1];
#pragma unroll 4
    for (int t = CHUNK - 1; t >= 0; --t) {
        bf16x2 lw = *(const bf16x2*)(lap + (size_t)t * 1024);
        bf16x2 gw = *(const bf16x2*)(gp + (size_t)t * 1024);
        h0 = fmaf(expf((float)lw[0]), h0, (float)gw[0]);
        h1 = fmaf(expf((float)lw[1]), h1, (float)gw[1]);
        bf16x2 ov; ov[0] = (bf16)h0; ov[1] = (bf16)h1;
        *(bf16x2*)(op + (size_t)t * 1024) = ov;
    }
}

extern "C" void kernel_launch(void* const* d_in, const int* in_sizes, int n_in,
                              void* d_out, int out_size, void* d_ws, size_t ws_size,
                              hipStream_t stream) {
    const float* x       = (const float*)d_in[0];
    const float* a_fwd   = (const float*)d_in[1];
    const float* Wf1     = (const float*)d_in[2];
    const float* bf1     = (const float*)d_in[3];
    const float* Wf2     = (const float*)d_in[4];
    const float* bf2     = (const float*)d_in[5];
    const float* Wbx     = (const float*)d_in[6];
    const float* bbx     = (const float*)d_in[7];
    const float* Wgx     = (const float*)d_in[8];
    const float* bgx     = (const float*)d_in[9];
    const float* Wga     = (const float*)d_in[10];
    const float* bga     = (const float*)d_in[11];
    const float* a_param = (const float*)d_in[12];
    const float* Wb2     = (const float*)d_in[13];
    const float* bb2     = (const float*)d_in[14];
    float* out = (float*)d_out;
    (void)in_sizes; (void)n_in; (void)out_size; (void)ws_size;

    // ---- workspace layout (~209 MB total) ----
    char* ws = (char*)d_ws;
    size_t off = 0;
    const size_t WSZ = (size_t)1024 * 1024 * 2;          // 2 MB per transposed weight
    bf16* Wf1t = (bf16*)(ws + off); off += WSZ;          // NOTE: Wf1t and Wbxt adjacent ->
    bf16* Wbxt = (bf16*)(ws + off); off += WSZ;          //       one [2048][1024] B for gemm_f01
    bf16* Wgxt = (bf16*)(ws + off); off += WSZ;
    bf16* Wgat = (bf16*)(ws + off); off += WSZ;
    bf16* Wf2t = (bf16*)(ws + off); off += WSZ;
    bf16* Wb2t = (bf16*)(ws + off); off += WSZ;
    float* spbuf = (float*)(ws + off); off += 4096;
    const size_t BSZ = (size_t)M_DIM * 1024 * 2;         // 64 MB bf16 [M][1024]
    bf16* buf0 = (bf16*)(ws + off); off += BSZ;          // xg -> hf
    bf16* buf1 = (bf16*)(ws + off); off += BSZ;          // v  -> hb
    bf16* buf2 = (bf16*)(ws + off); off += BSZ;          // la
    float* Fc = (float*)(ws + off); off += (size_t)NCHUNK * 8 * 1024 * 4;
    float* FH = (float*)(ws + off); off += (size_t)NCHUNK * 8 * 1024 * 4;
    float* BL = (float*)(ws + off); off += (size_t)NCHUNK * 8 * 1024 * 4;
    float* BP = (float*)(ws + off); off += (size_t)NCHUNK * 8 * 1024 * 4;
    float* BR = (float*)(ws + off); off += (size_t)NCHUNK * 8 * 1024 * 4;

    bf16* xg = buf0;
    bf16* hf = buf0;            // xg dead before hf written
    bf16* vb = buf1;
    bf16* hb = buf1;            // v dead before hb written
    bf16* la = buf2;
    bf16* ub = (bf16*)d_out;    // d_out as bf16 u scratch (dead before sc written)
    bf16* sc = (bf16*)d_out;    // then as bf16 sc scratch (dead before gemm_cat)

    // 1. prep: transposed bf16 weights + softplus(a_param)
    prep_weights<<<dim3(32, 32, 6), 256, 0, stream>>>(Wf1, Wbx, Wgx, Wga, Wf2, Wb2,
                                                      Wf1t, Wbxt, Wgxt, Wgat, Wf2t, Wb2t);
    sp_kernel<<<4, 256, 0, stream>>>(a_param, spbuf);
    // 2. gelu
    gelu_kernel<<<32768, 256, 0, stream>>>(x, xg);
    // 3+4. merged: u = bf16(xg@Wf1 + bf1) (into d_out) ; v = bf16(xg@Wbx + bbx)
    gemm_f01<<<2048, 512, 0, stream>>>(xg, Wf1t, ub, vb, bf1, bbx);
    // 5. forward scan -> hf (bf16, overwrites xg)
    fscan1<<<512, 256, 0, stream>>>(ub, a_fwd, Fc);
    fscan2<<<32, 256, 0, stream>>>(Fc, a_fwd, FH);
    fscan3<<<512, 256, 0, stream>>>(ub, a_fwd, FH, hf);
    // 6. gate a: la = -8*sigmoid(v@Wga+bga)*softplus(a_param)   (bf16)
    gemm_w<2><<<1024, 512, 0, stream>>>(vb, Wgat, la, bga, spbuf, nullptr, nullptr);
    // 7. gate x + scaled input: sc = sqrt(-expm1(2la))*sigmoid(v@Wgx+bgx)*v  (bf16, into d_out)
    gemm_w<3><<<1024, 512, 0, stream>>>(vb, Wgxt, sc, bgx, nullptr, la, vb);
    // 8. reverse scan -> hb (bf16, overwrites v)
    bscan1<<<512, 256, 0, stream>>>(la, sc, BL, BP);
    bscan2<<<32, 256, 0, stream>>>(BL, BP, BR);
    bscan3<<<512, 256, 0, stream>>>(la, sc, BR, hb);
    // 9+10. fused K=2048: out = hf@Wf2 + hb@Wb2 + bf2 + bb2 + x  (single f32 write)
    gemm_cat<<<1024, 512, 0, stream>>>(hf, hb, Wf2t, Wb2t, out, bf2, bb2, x);
}